// Round 1
// baseline (230.482 us; speedup 1.0000x reference)
//
#include <hip/hip_runtime.h>
#include <hip/hip_bf16.h>
#include <stdint.h>

// GPT causal self-attention block. B=8, T=1024, C=768, H=8, D=96. f32 I/O.
// bf16 MFMA pipeline with fp32 accumulation. Causal mask input ignored.
//
// This revision: swapped QK^T (mfma(K,Q)) makes softmax rows lane-local;
// V columns stored sigma-permuted so the PV A-fragment assembles from the
// lane's own registers (zero shuffles, no P LDS round-trip). Q pre-scaled
// by (1/sqrt(96))*log2(e) in the QKV GEMM so attention uses raw exp2.

typedef unsigned short ushort_t;
typedef __attribute__((ext_vector_type(8))) short short8;     // 8 bf16 = 4 VGPRs
typedef __attribute__((ext_vector_type(4))) float floatx4;    // MFMA C/D frag
typedef __attribute__((ext_vector_type(4))) unsigned short ushort4v;

#define MFMA16(a, b, c) __builtin_amdgcn_mfma_f32_16x16x32_bf16(a, b, c, 0, 0, 0)
#define NEG_BIG (-1e30f)

__device__ __forceinline__ unsigned short f2bf(float f) {
  union { float f; unsigned int u; } v; v.f = f;
  unsigned int r = (v.u + 0x7FFFu + ((v.u >> 16) & 1u)) >> 16;  // RNE
  return (unsigned short)r;
}

__device__ __forceinline__ unsigned int packbf2(float a, float b) {
  // low 16 = bf16(a), high 16 = bf16(b)  (v_cvt_pk_bf16_f32)
  union { __hip_bfloat162 h; unsigned int u; } cv;
  cv.h = __float22bfloat162_rn(make_float2(a, b));
  return cv.u;
}

// ---------------------------------------------------------------------------
// Fused f32->bf16 conversion for x, Wqkv, Wproj in one launch.
// Totals: 1572864 + 442368 + 147456 vec4 = 2162688 = 8448 * 256 exactly.
// ---------------------------------------------------------------------------
__global__ __launch_bounds__(256) void cvt3(
    const float* __restrict__ x, const float* __restrict__ wa,
    const float* __restrict__ wp, ushort_t* __restrict__ xb,
    ushort_t* __restrict__ wab, ushort_t* __restrict__ wpb)
{
  const int n1 = (8192 * 768) / 4, n2 = (2304 * 768) / 4;
  int i = blockIdx.x * 256 + threadIdx.x;
  const float* in; ushort_t* out;
  if (i < n1)            { in = x;  out = xb; }
  else if (i < n1 + n2)  { in = wa; out = wab; i -= n1; }
  else                   { in = wp; out = wpb; i -= (n1 + n2); }
  float4 v = *(const float4*)(in + (size_t)i * 4);
  ushort4v o;
  o.x = f2bf(v.x); o.y = f2bf(v.y); o.z = f2bf(v.z); o.w = f2bf(v.w);
  *(ushort4v*)(out + (size_t)i * 4) = o;
}

// ---------------------------------------------------------------------------
// QKV GEMM: qkv = x @ Wqkv^T + b. Q columns pre-scaled by (1/sqrt(96))*log2e.
// Writes q,k into QK (row stride 1536) and v TRANSPOSED into VT[b][h][d][T]
// with time index sigma-permuted within each 64-block (bits b4b3b2 -> b3b2b4)
// so attention's PV A-fragment needs no cross-lane P exchange.
// m97 structure: 128x128 tile, BK=32, global_load_lds width=16, 4 waves 2x2.
// ---------------------------------------------------------------------------
__global__ __launch_bounds__(256) void gemm_qkv(
    const ushort_t* __restrict__ A,   // 8192 x 768 bf16 (x)
    const ushort_t* __restrict__ W,   // 2304 x 768 bf16
    const float* __restrict__ bias,   // 2304 f32
    ushort_t* __restrict__ QK,        // 8192 x 1536 bf16
    ushort_t* __restrict__ VT)        // (64 bh) x 96 x 1024 bf16 (perm cols)
{
  const int K = 768;
  __shared__ ushort_t As[128 * 32];
  __shared__ ushort_t Bs[128 * 32];

  const int tid  = threadIdx.x;
  const int lane = tid & 63;
  const int l15  = lane & 15;
  const int quad = lane >> 4;
  const int wid  = tid >> 6;
  const int m0 = blockIdx.x * 128;
  const int n0 = blockIdx.y * 128;
  const int wm = (wid >> 1) * 64;
  const int wn = (wid & 1) * 64;
  const int srow = tid >> 2;
  const int scol = (tid & 3) * 8;

  floatx4 acc[4][4] = {};

  const ushort_t* gA = A + (size_t)(m0 + srow) * K + scol;
  const ushort_t* gB = W + (size_t)(n0 + srow) * K + scol;
  ushort_t* lA = &As[wid * 512];
  ushort_t* lB = &Bs[wid * 512];

  for (int k0 = 0; k0 < K; k0 += 32) {
    __builtin_amdgcn_global_load_lds(
        (const __attribute__((address_space(1))) void*)gA,
        (__attribute__((address_space(3))) void*)lA, 16, 0, 0);
    __builtin_amdgcn_global_load_lds(
        (const __attribute__((address_space(1))) void*)(gA + (size_t)64 * K),
        (__attribute__((address_space(3))) void*)(lA + 64 * 32), 16, 0, 0);
    __builtin_amdgcn_global_load_lds(
        (const __attribute__((address_space(1))) void*)gB,
        (__attribute__((address_space(3))) void*)lB, 16, 0, 0);
    __builtin_amdgcn_global_load_lds(
        (const __attribute__((address_space(1))) void*)(gB + (size_t)64 * K),
        (__attribute__((address_space(3))) void*)(lB + 64 * 32), 16, 0, 0);
    gA += 32; gB += 32;
    __syncthreads();

    short8 af[4], bf[4];
#pragma unroll
    for (int t = 0; t < 4; ++t)
      af[t] = *(const short8*)&As[(wm + t * 16 + l15) * 32 + quad * 8];
#pragma unroll
    for (int t = 0; t < 4; ++t)
      bf[t] = *(const short8*)&Bs[(wn + t * 16 + l15) * 32 + quad * 8];
#pragma unroll
    for (int tm = 0; tm < 4; ++tm)
#pragma unroll
      for (int tn = 0; tn < 4; ++tn)
        acc[tm][tn] = MFMA16(af[tm], bf[tn], acc[tm][tn]);
    __syncthreads();
  }

  const float QSCALE = 0.10206207261596577f * 1.4426950408889634f;

#pragma unroll
  for (int tn = 0; tn < 4; ++tn) {
    const int gc = n0 + wn + tn * 16 + l15;
    const float bv = bias[gc];
    const bool isv = (gc >= 1536);          // whole 16-col tile same side
    const bool isq = (gc < 768);
    const int hh = (gc - 1536) / 96, dd = (gc - 1536) % 96;
#pragma unroll
    for (int tm = 0; tm < 4; ++tm) {
      const int gr = m0 + wm + tm * 16 + quad * 4;
#pragma unroll
      for (int r = 0; r < 4; ++r) {
        float val = acc[tm][tn][r] + bv;
        const int row = gr + r;
        if (!isv) {
          if (isq) val *= QSCALE;
          QK[(size_t)row * 1536 + gc] = f2bf(val);
        } else {
          const int bb = row >> 10, tt = row & 1023;
          // sigma: bit2 <- tt.bit4, bits4..3 <- tt.bits3..2 (bits 0,1,5.. keep)
          const int tt2 = (tt & ~0x1C) | (((tt >> 4) & 1) << 2) |
                          (((tt >> 2) & 3) << 3);
          VT[(((size_t)(bb * 8 + hh)) * 96 + dd) * 1024 + tt2] = f2bf(val);
        }
      }
    }
  }
}

// ---------------------------------------------------------------------------
// Generic GEMM (proj): C[m][n] = sum_k A[m][k] W[n][k] + bias[n], f32 out.
// ---------------------------------------------------------------------------
__global__ __launch_bounds__(256) void gemm_proj(
    const ushort_t* __restrict__ A,   // M x K bf16
    const ushort_t* __restrict__ W,   // N x K bf16
    const float* __restrict__ bias,   // N f32
    float* __restrict__ C,            // M x N f32
    int M, int N, int K)
{
  __shared__ ushort_t As[128 * 32];
  __shared__ ushort_t Bs[128 * 32];

  const int tid  = threadIdx.x;
  const int lane = tid & 63;
  const int l15  = lane & 15;
  const int quad = lane >> 4;
  const int wid  = tid >> 6;
  const int m0 = blockIdx.x * 128;
  const int n0 = blockIdx.y * 128;
  const int wm = (wid >> 1) * 64;
  const int wn = (wid & 1) * 64;
  const int srow = tid >> 2;
  const int scol = (tid & 3) * 8;

  floatx4 acc[4][4] = {};

  const ushort_t* gA = A + (size_t)(m0 + srow) * K + scol;
  const ushort_t* gB = W + (size_t)(n0 + srow) * K + scol;
  ushort_t* lA = &As[wid * 512];
  ushort_t* lB = &Bs[wid * 512];

  for (int k0 = 0; k0 < K; k0 += 32) {
    __builtin_amdgcn_global_load_lds(
        (const __attribute__((address_space(1))) void*)gA,
        (__attribute__((address_space(3))) void*)lA, 16, 0, 0);
    __builtin_amdgcn_global_load_lds(
        (const __attribute__((address_space(1))) void*)(gA + (size_t)64 * K),
        (__attribute__((address_space(3))) void*)(lA + 64 * 32), 16, 0, 0);
    __builtin_amdgcn_global_load_lds(
        (const __attribute__((address_space(1))) void*)gB,
        (__attribute__((address_space(3))) void*)lB, 16, 0, 0);
    __builtin_amdgcn_global_load_lds(
        (const __attribute__((address_space(1))) void*)(gB + (size_t)64 * K),
        (__attribute__((address_space(3))) void*)(lB + 64 * 32), 16, 0, 0);
    gA += 32; gB += 32;
    __syncthreads();

    short8 af[4], bf[4];
#pragma unroll
    for (int t = 0; t < 4; ++t)
      af[t] = *(const short8*)&As[(wm + t * 16 + l15) * 32 + quad * 8];
#pragma unroll
    for (int t = 0; t < 4; ++t)
      bf[t] = *(const short8*)&Bs[(wn + t * 16 + l15) * 32 + quad * 8];
#pragma unroll
    for (int tm = 0; tm < 4; ++tm)
#pragma unroll
      for (int tn = 0; tn < 4; ++tn)
        acc[tm][tn] = MFMA16(af[tm], bf[tn], acc[tm][tn]);
    __syncthreads();
  }

#pragma unroll
  for (int tn = 0; tn < 4; ++tn) {
    const int gc = n0 + wn + tn * 16 + l15;
    const float bv = bias[gc];
#pragma unroll
    for (int tm = 0; tm < 4; ++tm) {
      const int gr = m0 + wm + tm * 16 + quad * 4;
#pragma unroll
      for (int r = 0; r < 4; ++r)
        C[(size_t)(gr + r) * N + gc] = acc[tm][tn][r] + bv;
    }
  }
}

// ---------------------------------------------------------------------------
// Fused causal flash attention, swapped-QK^T form.
// Grid (16, 64): block = (b,h) + paired q-chunks cA=bx, cB=31-bx (32 rows ea).
// Waves 0,1 -> chunk A rows; waves 2,3 -> chunk B rows (16 q-rows per wave).
// BK=64 keys/tile. K staged via global_load_lds (packed [key][96]); V^T staged
// from pre-permuted VT with padded rows (72) for conflict-free b128 reads.
//
// QK^T computed as mfma(K, Q): s[t] row=quad*4+j = key t*16+quad*4+j,
// col=l15 = q-row q0w+l15. Softmax per-row is lane-local (+2 shfl_xor for
// cross-quad). PV A-frag slots (u,quad,e) map to key (2u+(e>>2))*16+quad*4+
// (e&3) = exactly this lane's register set; V columns pre-permuted to match.
// O layout: row=quad*4+j = q-row, col=l15 = d (same as before).
// ---------------------------------------------------------------------------
__global__ __launch_bounds__(256) void attn_fused(
    const ushort_t* __restrict__ QK,   // (B*T) x 1536 bf16  [q*scale | k]
    const ushort_t* __restrict__ VT,   // (64 bh) x 96 x 1024 bf16 (perm cols)
    ushort_t* __restrict__ y)          // (B*T) x 768 bf16
{
  __shared__ ushort_t Ks[64 * 96];     // packed: global_load_lds target
  __shared__ ushort_t Vt[96 * 72];     // padded rows (72) for b128 reads

  const int tid  = threadIdx.x;
  const int lane = tid & 63;
  const int l15  = lane & 15;
  const int quad = lane >> 4;
  const int wid  = tid >> 6;
  const int bh = blockIdx.y;
  const int b = bh >> 3;
  const int h = bh & 7;
  const int qoff = h * 96;

  const int cA = blockIdx.x;           // 0..15
  const int cB = 31 - cA;              // 16..31
  const int myChunk = (wid < 2) ? cA : cB;
  const int q0w = myChunk * 32 + (wid & 1) * 16;   // wave's first q row
  const int kend = cB * 32 + 32;                   // loop bound (chunk B)
  const int rq = q0w + l15;                        // this lane's q row

  const size_t rowbase = (size_t)b * 1024;
  const ushort_t* vtb = VT + (size_t)bh * 96 * 1024;

  // Q fragments (used as B operand), K=96 in 3 chunks of 32
  short8 qf[3];
#pragma unroll
  for (int c = 0; c < 3; ++c)
    qf[c] = *(const short8*)(QK + (rowbase + q0w + l15) * 1536 + qoff +
                             c * 32 + quad * 8);

  float m_i = NEG_BIG;   // running max for row l15 (exp2 domain)
  float l_i = 0.f;       // running denom for row l15
  floatx4 O[6] = {};

  for (int k0 = 0; k0 < kend; k0 += 64) {
    // --- stage K tile [64][96] via global_load_lds (wave w -> keys w*16..+16)
#pragma unroll
    for (int i = 0; i < 3; ++i) {
      const int e = wid * 1536 + i * 512 + lane * 8;
      const int kr = e / 96, kc = e % 96;
      __builtin_amdgcn_global_load_lds(
          (const __attribute__((address_space(1))) void*)
              (QK + (rowbase + k0 + kr) * 1536 + 768 + qoff + kc),
          (__attribute__((address_space(3))) void*)(&Ks[wid * 1536 + i * 512]),
          16, 0, 0);
    }
    // --- stage V^T tile [96][64] -> padded LDS rows of 72 (cols pre-permuted)
#pragma unroll
    for (int g = 0; g < 3; ++g) {
      const int d = g * 32 + (tid >> 3);
      const int kc = (tid & 7) * 8;
      short8 v = *(const short8*)(vtb + (size_t)d * 1024 + k0 + kc);
      *(short8*)&Vt[d * 72 + kc] = v;
    }
    __syncthreads();

    if (k0 < q0w + 16) {  // wave-uniform activity test
      // QK^T swapped: s[t] = K_tile(t) * Q  -> rows=keys, cols=q
      floatx4 s[4] = {};
#pragma unroll
      for (int t = 0; t < 4; ++t) {
#pragma unroll
        for (int c = 0; c < 3; ++c) {
          short8 kf = *(const short8*)&Ks[(t * 16 + l15) * 96 + c * 32 + quad * 8];
          s[t] = MFMA16(kf, qf[c], s[t]);
        }
      }
      // scores for row rq: key = k0 + t*16 + quad*4 + j
      float p[4][4];
      if (k0 + 64 <= q0w) {            // fully unmasked tile (fast path)
#pragma unroll
        for (int t = 0; t < 4; ++t)
#pragma unroll
          for (int j = 0; j < 4; ++j) p[t][j] = s[t][j];
      } else {                          // diagonal tile: causal mask
        const int kq = k0 + quad * 4;
#pragma unroll
        for (int t = 0; t < 4; ++t)
#pragma unroll
          for (int j = 0; j < 4; ++j)
            p[t][j] = (kq + t * 16 + j <= rq) ? s[t][j] : NEG_BIG;
      }
      // row max: in-lane tree (16) + cross-quad
      float m0v = fmaxf(fmaxf(p[0][0], p[0][1]), fmaxf(p[0][2], p[0][3]));
      float m1v = fmaxf(fmaxf(p[1][0], p[1][1]), fmaxf(p[1][2], p[1][3]));
      float m2v = fmaxf(fmaxf(p[2][0], p[2][1]), fmaxf(p[2][2], p[2][3]));
      float m3v = fmaxf(fmaxf(p[3][0], p[3][1]), fmaxf(p[3][2], p[3][3]));
      float mt = fmaxf(fmaxf(m0v, m1v), fmaxf(m2v, m3v));
      mt = fmaxf(mt, __shfl_xor(mt, 16));
      mt = fmaxf(mt, __shfl_xor(mt, 32));
      // defer-max: only rescale when max grew by > 8 (exp2 headroom 2^8)
      if (!__all(mt - m_i <= 8.0f)) {
        const float mn = fmaxf(m_i, mt);
        const float al = __builtin_amdgcn_exp2f(m_i - mn);
        m_i = mn;
        l_i *= al;
#pragma unroll
        for (int j = 0; j < 4; ++j) {
          const float alr = __shfl(al, quad * 4 + j);  // al of O-row quad*4+j
#pragma unroll
          for (int f = 0; f < 6; ++f) O[f][j] *= alr;
        }
      }
      float rs = 0.f;
#pragma unroll
      for (int t = 0; t < 4; ++t)
#pragma unroll
        for (int j = 0; j < 4; ++j) {
          p[t][j] = __builtin_amdgcn_exp2f(p[t][j] - m_i);
          rs += p[t][j];
        }
      rs += __shfl_xor(rs, 16);
      rs += __shfl_xor(rs, 32);
      l_i += rs;
      // pack P to bf16 A-frags entirely in-lane (keys pre-permuted into V)
      union { short8 s8; unsigned int u[4]; } pf0, pf1;
      pf0.u[0] = packbf2(p[0][0], p[0][1]);
      pf0.u[1] = packbf2(p[0][2], p[0][3]);
      pf0.u[2] = packbf2(p[1][0], p[1][1]);
      pf0.u[3] = packbf2(p[1][2], p[1][3]);
      pf1.u[0] = packbf2(p[2][0], p[2][1]);
      pf1.u[1] = packbf2(p[2][2], p[2][3]);
      pf1.u[2] = packbf2(p[3][0], p[3][1]);
      pf1.u[3] = packbf2(p[3][2], p[3][3]);
#pragma unroll
      for (int f = 0; f < 6; ++f) {
        short8 vf0 = *(const short8*)&Vt[(f * 16 + l15) * 72 + quad * 8];
        O[f] = MFMA16(pf0.s8, vf0, O[f]);
        short8 vf1 = *(const short8*)&Vt[(f * 16 + l15) * 72 + 32 + quad * 8];
        O[f] = MFMA16(pf1.s8, vf1, O[f]);
      }
    }
    __syncthreads();
  }

  // epilogue: O rows are quad*4+j; softmax denom lives in lane (row)
  float inv[4];
#pragma unroll
  for (int j = 0; j < 4; ++j) {
    const float lj = __shfl(l_i, quad * 4 + j);
    inv[j] = 1.0f / fmaxf(lj, 1e-20f);
  }
#pragma unroll
  for (int j = 0; j < 4; ++j) {
    const size_t row = rowbase + q0w + quad * 4 + j;
#pragma unroll
    for (int f = 0; f < 6; ++f)
      y[row * 768 + qoff + f * 16 + l15] = f2bf(O[f][j] * inv[j]);
  }
}

// ---------------------------------------------------------------------------
extern "C" void kernel_launch(void* const* d_in, const int* in_sizes, int n_in,
                              void* d_out, int out_size, void* d_ws, size_t ws_size,
                              hipStream_t stream)
{
  const float* x_f  = (const float*)d_in[0];
  const float* wa_f = (const float*)d_in[1];
  const float* ba_f = (const float*)d_in[2];
  const float* wp_f = (const float*)d_in[3];
  const float* bp_f = (const float*)d_in[4];
  float* out = (float*)d_out;

  ushort_t* xb  = (ushort_t*)d_ws;                    // 8192 x  768
  ushort_t* wab = xb  + (size_t)8192 * 768;           // 2304 x  768
  ushort_t* wpb = wab + (size_t)2304 * 768;           //  768 x  768
  ushort_t* QK  = wpb + (size_t)768 * 768;            // 8192 x 1536
  ushort_t* VT  = QK  + (size_t)8192 * 1536;          // 64 x 96 x 1024
  ushort_t* yw  = VT  + (size_t)8192 * 768;           // 8192 x  768

  // (8192*768 + 2304*768 + 768*768)/4 = 2162688 = 8448 * 256
  cvt3<<<8448, 256, 0, stream>>>(x_f, wa_f, wp_f, xb, wab, wpb);

  gemm_qkv<<<dim3(64, 18), 256, 0, stream>>>(xb, wab, ba_f, QK, VT);
  attn_fused<<<dim3(16, 64), 256, 0, stream>>>(QK, VT, yw);
  gemm_proj<<<dim3(64, 6), 256, 0, stream>>>(yw, wpb, bp_f, out,
                                             8192, 768, 768);
}

// Round 2
// 227.578 us; speedup vs baseline: 1.0128x; 1.0128x over previous
//
#include <hip/hip_runtime.h>
#include <hip/hip_bf16.h>
#include <stdint.h>

// GPT causal self-attention block. B=8, T=1024, C=768, H=8, D=96. f32 I/O.
// bf16 MFMA pipeline with fp32 accumulation. Causal mask input ignored.
//
// R1: double-buffered prefetch pipeline (T3-minimal) in both GEMMs and the
// fused attention: issue next-tile staging BEFORE computing the current tile,
// one barrier drain per iteration. Previously loads were issued immediately
// before the vmcnt(0) drain -> full latency exposed every K-step.

typedef unsigned short ushort_t;
typedef __attribute__((ext_vector_type(8))) short short8;     // 8 bf16 = 4 VGPRs
typedef __attribute__((ext_vector_type(4))) float floatx4;    // MFMA C/D frag
typedef __attribute__((ext_vector_type(4))) unsigned short ushort4v;

#define MFMA16(a, b, c) __builtin_amdgcn_mfma_f32_16x16x32_bf16(a, b, c, 0, 0, 0)
#define NEG_BIG (-1e30f)

__device__ __forceinline__ unsigned short f2bf(float f) {
  union { float f; unsigned int u; } v; v.f = f;
  unsigned int r = (v.u + 0x7FFFu + ((v.u >> 16) & 1u)) >> 16;  // RNE
  return (unsigned short)r;
}

__device__ __forceinline__ unsigned int packbf2(float a, float b) {
  // low 16 = bf16(a), high 16 = bf16(b)  (v_cvt_pk_bf16_f32)
  union { __hip_bfloat162 h; unsigned int u; } cv;
  cv.h = __float22bfloat162_rn(make_float2(a, b));
  return cv.u;
}

#define GLOAD16(src, dst)                                              \
  __builtin_amdgcn_global_load_lds(                                    \
      (const __attribute__((address_space(1))) void*)(src),            \
      (__attribute__((address_space(3))) void*)(dst), 16, 0, 0)

// ---------------------------------------------------------------------------
// Fused f32->bf16 conversion for x, Wqkv, Wproj in one launch.
// Totals: 1572864 + 442368 + 147456 vec4 = 2162688 = 8448 * 256 exactly.
// ---------------------------------------------------------------------------
__global__ __launch_bounds__(256) void cvt3(
    const float* __restrict__ x, const float* __restrict__ wa,
    const float* __restrict__ wp, ushort_t* __restrict__ xb,
    ushort_t* __restrict__ wab, ushort_t* __restrict__ wpb)
{
  const int n1 = (8192 * 768) / 4, n2 = (2304 * 768) / 4;
  int i = blockIdx.x * 256 + threadIdx.x;
  const float* in; ushort_t* out;
  if (i < n1)            { in = x;  out = xb; }
  else if (i < n1 + n2)  { in = wa; out = wab; i -= n1; }
  else                   { in = wp; out = wpb; i -= (n1 + n2); }
  float4 v = *(const float4*)(in + (size_t)i * 4);
  ushort4v o;
  o.x = f2bf(v.x); o.y = f2bf(v.y); o.z = f2bf(v.z); o.w = f2bf(v.w);
  *(ushort4v*)(out + (size_t)i * 4) = o;
}

// ---------------------------------------------------------------------------
// QKV GEMM: qkv = x @ Wqkv^T + b. Q columns pre-scaled by (1/sqrt(96))*log2e.
// Writes q,k into QK (row stride 1536) and v TRANSPOSED into VT[b][h][d][T]
// with time index sigma-permuted within each 64-block (bits b4b3b2 -> b3b2b4)
// so attention's PV A-fragment needs no cross-lane P exchange.
// 128x128 tile, BK=32, global_load_lds width=16, 4 waves 2x2, LDS dbuf.
// ---------------------------------------------------------------------------
__global__ __launch_bounds__(256) void gemm_qkv(
    const ushort_t* __restrict__ A,   // 8192 x 768 bf16 (x)
    const ushort_t* __restrict__ W,   // 2304 x 768 bf16
    const float* __restrict__ bias,   // 2304 f32
    ushort_t* __restrict__ QK,        // 8192 x 1536 bf16
    ushort_t* __restrict__ VT)        // (64 bh) x 96 x 1024 bf16 (perm cols)
{
  const int K = 768;
  __shared__ ushort_t As[2][128 * 32];
  __shared__ ushort_t Bs[2][128 * 32];

  const int tid  = threadIdx.x;
  const int lane = tid & 63;
  const int l15  = lane & 15;
  const int quad = lane >> 4;
  const int wid  = tid >> 6;
  const int m0 = blockIdx.x * 128;
  const int n0 = blockIdx.y * 128;
  const int wm = (wid >> 1) * 64;
  const int wn = (wid & 1) * 64;
  const int srow = tid >> 2;
  const int scol = (tid & 3) * 8;

  floatx4 acc[4][4] = {};

  const ushort_t* gA = A + (size_t)(m0 + srow) * K + scol;
  const ushort_t* gB = W + (size_t)(n0 + srow) * K + scol;

  // prologue: stage tile 0 into buffer 0
  {
    ushort_t* lA = &As[0][wid * 512];
    ushort_t* lB = &Bs[0][wid * 512];
    GLOAD16(gA, lA);
    GLOAD16(gA + (size_t)64 * K, lA + 64 * 32);
    GLOAD16(gB, lB);
    GLOAD16(gB + (size_t)64 * K, lB + 64 * 32);
  }
  __syncthreads();

  int cur = 0;
  for (int k0 = 0; k0 < K; k0 += 32) {
    if (k0 + 32 < K) {  // issue next-tile staging BEFORE compute
      ushort_t* lA = &As[cur ^ 1][wid * 512];
      ushort_t* lB = &Bs[cur ^ 1][wid * 512];
      const ushort_t* pA = gA + k0 + 32;
      const ushort_t* pB = gB + k0 + 32;
      GLOAD16(pA, lA);
      GLOAD16(pA + (size_t)64 * K, lA + 64 * 32);
      GLOAD16(pB, lB);
      GLOAD16(pB + (size_t)64 * K, lB + 64 * 32);
    }

    short8 af[4], bf[4];
#pragma unroll
    for (int t = 0; t < 4; ++t)
      af[t] = *(const short8*)&As[cur][(wm + t * 16 + l15) * 32 + quad * 8];
#pragma unroll
    for (int t = 0; t < 4; ++t)
      bf[t] = *(const short8*)&Bs[cur][(wn + t * 16 + l15) * 32 + quad * 8];
#pragma unroll
    for (int tm = 0; tm < 4; ++tm)
#pragma unroll
      for (int tn = 0; tn < 4; ++tn)
        acc[tm][tn] = MFMA16(af[tm], bf[tn], acc[tm][tn]);
    __syncthreads();   // drains next-tile loads (they had the compute to land)
    cur ^= 1;
  }

  const float QSCALE = 0.10206207261596577f * 1.4426950408889634f;

#pragma unroll
  for (int tn = 0; tn < 4; ++tn) {
    const int gc = n0 + wn + tn * 16 + l15;
    const float bv = bias[gc];
    const bool isv = (gc >= 1536);          // whole 16-col tile same side
    const bool isq = (gc < 768);
    const int hh = (gc - 1536) / 96, dd = (gc - 1536) % 96;
#pragma unroll
    for (int tm = 0; tm < 4; ++tm) {
      const int gr = m0 + wm + tm * 16 + quad * 4;
#pragma unroll
      for (int r = 0; r < 4; ++r) {
        float val = acc[tm][tn][r] + bv;
        const int row = gr + r;
        if (!isv) {
          if (isq) val *= QSCALE;
          QK[(size_t)row * 1536 + gc] = f2bf(val);
        } else {
          const int bb = row >> 10, tt = row & 1023;
          // sigma: bit2 <- tt.bit4, bits4..3 <- tt.bits3..2 (bits 0,1,5.. keep)
          const int tt2 = (tt & ~0x1C) | (((tt >> 4) & 1) << 2) |
                          (((tt >> 2) & 3) << 3);
          VT[(((size_t)(bb * 8 + hh)) * 96 + dd) * 1024 + tt2] = f2bf(val);
        }
      }
    }
  }
}

// ---------------------------------------------------------------------------
// Generic GEMM (proj): C[m][n] = sum_k A[m][k] W[n][k] + bias[n], f32 out.
// Same dbuf pipeline.
// ---------------------------------------------------------------------------
__global__ __launch_bounds__(256) void gemm_proj(
    const ushort_t* __restrict__ A,   // M x K bf16
    const ushort_t* __restrict__ W,   // N x K bf16
    const float* __restrict__ bias,   // N f32
    float* __restrict__ C,            // M x N f32
    int M, int N, int K)
{
  __shared__ ushort_t As[2][128 * 32];
  __shared__ ushort_t Bs[2][128 * 32];

  const int tid  = threadIdx.x;
  const int lane = tid & 63;
  const int l15  = lane & 15;
  const int quad = lane >> 4;
  const int wid  = tid >> 6;
  const int m0 = blockIdx.x * 128;
  const int n0 = blockIdx.y * 128;
  const int wm = (wid >> 1) * 64;
  const int wn = (wid & 1) * 64;
  const int srow = tid >> 2;
  const int scol = (tid & 3) * 8;

  floatx4 acc[4][4] = {};

  const ushort_t* gA = A + (size_t)(m0 + srow) * K + scol;
  const ushort_t* gB = W + (size_t)(n0 + srow) * K + scol;

  {
    ushort_t* lA = &As[0][wid * 512];
    ushort_t* lB = &Bs[0][wid * 512];
    GLOAD16(gA, lA);
    GLOAD16(gA + (size_t)64 * K, lA + 64 * 32);
    GLOAD16(gB, lB);
    GLOAD16(gB + (size_t)64 * K, lB + 64 * 32);
  }
  __syncthreads();

  int cur = 0;
  for (int k0 = 0; k0 < K; k0 += 32) {
    if (k0 + 32 < K) {
      ushort_t* lA = &As[cur ^ 1][wid * 512];
      ushort_t* lB = &Bs[cur ^ 1][wid * 512];
      const ushort_t* pA = gA + k0 + 32;
      const ushort_t* pB = gB + k0 + 32;
      GLOAD16(pA, lA);
      GLOAD16(pA + (size_t)64 * K, lA + 64 * 32);
      GLOAD16(pB, lB);
      GLOAD16(pB + (size_t)64 * K, lB + 64 * 32);
    }

    short8 af[4], bf[4];
#pragma unroll
    for (int t = 0; t < 4; ++t)
      af[t] = *(const short8*)&As[cur][(wm + t * 16 + l15) * 32 + quad * 8];
#pragma unroll
    for (int t = 0; t < 4; ++t)
      bf[t] = *(const short8*)&Bs[cur][(wn + t * 16 + l15) * 32 + quad * 8];
#pragma unroll
    for (int tm = 0; tm < 4; ++tm)
#pragma unroll
      for (int tn = 0; tn < 4; ++tn)
        acc[tm][tn] = MFMA16(af[tm], bf[tn], acc[tm][tn]);
    __syncthreads();
    cur ^= 1;
  }

#pragma unroll
  for (int tn = 0; tn < 4; ++tn) {
    const int gc = n0 + wn + tn * 16 + l15;
    const float bv = bias[gc];
#pragma unroll
    for (int tm = 0; tm < 4; ++tm) {
      const int gr = m0 + wm + tm * 16 + quad * 4;
#pragma unroll
      for (int r = 0; r < 4; ++r)
        C[(size_t)(gr + r) * N + gc] = acc[tm][tn][r] + bv;
    }
  }
}

// ---------------------------------------------------------------------------
// Fused causal flash attention, swapped-QK^T form, double-buffered staging.
// Grid (16, 64): block = (b,h) + paired q-chunks cA=bx, cB=31-bx (32 rows ea).
// Waves 0,1 -> chunk A rows; waves 2,3 -> chunk B rows (16 q-rows per wave).
// BK=64 keys/tile. K staged via global_load_lds (packed [key][96]); V^T staged
// from pre-permuted VT with padded rows (72) for conflict-free b128 reads.
// Pipeline: issue K gloads + V reg-loads for tile t+1, compute tile t,
// ds_write V(t+1), one barrier per iteration (T14 issue-early/write-late).
// ---------------------------------------------------------------------------
__global__ __launch_bounds__(256) void attn_fused(
    const ushort_t* __restrict__ QK,   // (B*T) x 1536 bf16  [q*scale | k]
    const ushort_t* __restrict__ VT,   // (64 bh) x 96 x 1024 bf16 (perm cols)
    ushort_t* __restrict__ y)          // (B*T) x 768 bf16
{
  __shared__ ushort_t Ks[2][64 * 96];  // packed: global_load_lds target
  __shared__ ushort_t Vt[2][96 * 72];  // padded rows (72) for b128 reads

  const int tid  = threadIdx.x;
  const int lane = tid & 63;
  const int l15  = lane & 15;
  const int quad = lane >> 4;
  const int wid  = tid >> 6;
  const int bh = blockIdx.y;
  const int b = bh >> 3;
  const int h = bh & 7;
  const int qoff = h * 96;

  const int cA = blockIdx.x;           // 0..15
  const int cB = 31 - cA;              // 16..31
  const int myChunk = (wid < 2) ? cA : cB;
  const int q0w = myChunk * 32 + (wid & 1) * 16;   // wave's first q row
  const int kend = cB * 32 + 32;                   // loop bound (chunk B)
  const int rq = q0w + l15;                        // this lane's q row

  const size_t rowbase = (size_t)b * 1024;
  const ushort_t* vtb = VT + (size_t)bh * 96 * 1024;

  // per-thread staging coords
  const int ke0 = wid * 1536 + lane * 8;           // K-stage element base
  const int vd  = (tid >> 3);                      // V-stage row within group
  const int vkc = (tid & 7) * 8;                   // V-stage col

  // Q fragments (used as B operand), K=96 in 3 chunks of 32
  short8 qf[3];
#pragma unroll
  for (int c = 0; c < 3; ++c)
    qf[c] = *(const short8*)(QK + (rowbase + q0w + l15) * 1536 + qoff +
                             c * 32 + quad * 8);

  float m_i = NEG_BIG;   // running max for row l15 (exp2 domain)
  float l_i = 0.f;       // running denom for row l15
  floatx4 O[6] = {};

  // prologue: stage tile 0 into buffer 0
  {
#pragma unroll
    for (int i = 0; i < 3; ++i) {
      const int e = ke0 + i * 512;
      const int kr = e / 96, kc = e % 96;
      GLOAD16(QK + (rowbase + kr) * 1536 + 768 + qoff + kc,
              &Ks[0][wid * 1536 + i * 512]);
    }
#pragma unroll
    for (int g = 0; g < 3; ++g) {
      const int d = g * 32 + vd;
      short8 v = *(const short8*)(vtb + (size_t)d * 1024 + vkc);
      *(short8*)&Vt[0][d * 72 + vkc] = v;
    }
  }
  __syncthreads();

  int cur = 0;
  for (int k0 = 0; k0 < kend; k0 += 64) {
    const int nk = k0 + 64;
    const bool more = (nk < kend);

    // issue next tile's K staging (async) + V global loads (to regs)
    short8 vreg[3];
    if (more) {
#pragma unroll
      for (int i = 0; i < 3; ++i) {
        const int e = ke0 + i * 512;
        const int kr = e / 96, kc = e % 96;
        GLOAD16(QK + (rowbase + nk + kr) * 1536 + 768 + qoff + kc,
                &Ks[cur ^ 1][wid * 1536 + i * 512]);
      }
#pragma unroll
      for (int g = 0; g < 3; ++g)
        vreg[g] = *(const short8*)(vtb + (size_t)(g * 32 + vd) * 1024 + nk + vkc);
    }

    if (k0 < q0w + 16) {  // wave-uniform activity test
      // QK^T swapped: s[t] = K_tile(t) * Q  -> rows=keys, cols=q
      floatx4 s[4] = {};
#pragma unroll
      for (int t = 0; t < 4; ++t) {
#pragma unroll
        for (int c = 0; c < 3; ++c) {
          short8 kf = *(const short8*)
              &Ks[cur][(t * 16 + l15) * 96 + c * 32 + quad * 8];
          s[t] = MFMA16(kf, qf[c], s[t]);
        }
      }
      // scores for row rq: key = k0 + t*16 + quad*4 + j
      float p[4][4];
      if (k0 + 64 <= q0w) {            // fully unmasked tile (fast path)
#pragma unroll
        for (int t = 0; t < 4; ++t)
#pragma unroll
          for (int j = 0; j < 4; ++j) p[t][j] = s[t][j];
      } else {                          // diagonal tile: causal mask
        const int kq = k0 + quad * 4;
#pragma unroll
        for (int t = 0; t < 4; ++t)
#pragma unroll
          for (int j = 0; j < 4; ++j)
            p[t][j] = (kq + t * 16 + j <= rq) ? s[t][j] : NEG_BIG;
      }
      // row max: in-lane tree (16) + cross-quad
      float m0v = fmaxf(fmaxf(p[0][0], p[0][1]), fmaxf(p[0][2], p[0][3]));
      float m1v = fmaxf(fmaxf(p[1][0], p[1][1]), fmaxf(p[1][2], p[1][3]));
      float m2v = fmaxf(fmaxf(p[2][0], p[2][1]), fmaxf(p[2][2], p[2][3]));
      float m3v = fmaxf(fmaxf(p[3][0], p[3][1]), fmaxf(p[3][2], p[3][3]));
      float mt = fmaxf(fmaxf(m0v, m1v), fmaxf(m2v, m3v));
      mt = fmaxf(mt, __shfl_xor(mt, 16));
      mt = fmaxf(mt, __shfl_xor(mt, 32));
      // defer-max: only rescale when max grew by > 8 (exp2 headroom 2^8)
      if (!__all(mt - m_i <= 8.0f)) {
        const float mn = fmaxf(m_i, mt);
        const float al = __builtin_amdgcn_exp2f(m_i - mn);
        m_i = mn;
        l_i *= al;
#pragma unroll
        for (int j = 0; j < 4; ++j) {
          const float alr = __shfl(al, quad * 4 + j);  // al of O-row quad*4+j
#pragma unroll
          for (int f = 0; f < 6; ++f) O[f][j] *= alr;
        }
      }
      float rs = 0.f;
#pragma unroll
      for (int t = 0; t < 4; ++t)
#pragma unroll
        for (int j = 0; j < 4; ++j) {
          p[t][j] = __builtin_amdgcn_exp2f(p[t][j] - m_i);
          rs += p[t][j];
        }
      rs += __shfl_xor(rs, 16);
      rs += __shfl_xor(rs, 32);
      l_i += rs;
      // pack P to bf16 A-frags entirely in-lane (keys pre-permuted into V)
      union { short8 s8; unsigned int u[4]; } pf0, pf1;
      pf0.u[0] = packbf2(p[0][0], p[0][1]);
      pf0.u[1] = packbf2(p[0][2], p[0][3]);
      pf0.u[2] = packbf2(p[1][0], p[1][1]);
      pf0.u[3] = packbf2(p[1][2], p[1][3]);
      pf1.u[0] = packbf2(p[2][0], p[2][1]);
      pf1.u[1] = packbf2(p[2][2], p[2][3]);
      pf1.u[2] = packbf2(p[3][0], p[3][1]);
      pf1.u[3] = packbf2(p[3][2], p[3][3]);
#pragma unroll
      for (int f = 0; f < 6; ++f) {
        short8 vf0 = *(const short8*)&Vt[cur][(f * 16 + l15) * 72 + quad * 8];
        O[f] = MFMA16(pf0.s8, vf0, O[f]);
        short8 vf1 = *(const short8*)
            &Vt[cur][(f * 16 + l15) * 72 + 32 + quad * 8];
        O[f] = MFMA16(pf1.s8, vf1, O[f]);
      }
    }

    // write-late: V(t+1) regs -> LDS (vmcnt waits land here, after compute)
    if (more) {
#pragma unroll
      for (int g = 0; g < 3; ++g)
        *(short8*)&Vt[cur ^ 1][(g * 32 + vd) * 72 + vkc] = vreg[g];
    }
    __syncthreads();
    cur ^= 1;
  }

  // epilogue: O rows are quad*4+j; softmax denom lives in lane (row)
  float inv[4];
#pragma unroll
  for (int j = 0; j < 4; ++j) {
    const float lj = __shfl(l_i, quad * 4 + j);
    inv[j] = 1.0f / fmaxf(lj, 1e-20f);
  }
#pragma unroll
  for (int j = 0; j < 4; ++j) {
    const size_t row = rowbase + q0w + quad * 4 + j;
#pragma unroll
    for (int f = 0; f < 6; ++f)
      y[row * 768 + qoff + f * 16 + l15] = f2bf(O[f][j] * inv[j]);
  }
}

// ---------------------------------------------------------------------------
extern "C" void kernel_launch(void* const* d_in, const int* in_sizes, int n_in,
                              void* d_out, int out_size, void* d_ws, size_t ws_size,
                              hipStream_t stream)
{
  const float* x_f  = (const float*)d_in[0];
  const float* wa_f = (const float*)d_in[1];
  const float* ba_f = (const float*)d_in[2];
  const float* wp_f = (const float*)d_in[3];
  const float* bp_f = (const float*)d_in[4];
  float* out = (float*)d_out;

  ushort_t* xb  = (ushort_t*)d_ws;                    // 8192 x  768
  ushort_t* wab = xb  + (size_t)8192 * 768;           // 2304 x  768
  ushort_t* wpb = wab + (size_t)2304 * 768;           //  768 x  768
  ushort_t* QK  = wpb + (size_t)768 * 768;            // 8192 x 1536
  ushort_t* VT  = QK  + (size_t)8192 * 1536;          // 64 x 96 x 1024
  ushort_t* yw  = VT  + (size_t)8192 * 768;           // 8192 x  768

  // (8192*768 + 2304*768 + 768*768)/4 = 2162688 = 8448 * 256
  cvt3<<<8448, 256, 0, stream>>>(x_f, wa_f, wp_f, xb, wab, wpb);

  gemm_qkv<<<dim3(64, 18), 256, 0, stream>>>(xb, wab, ba_f, QK, VT);
  attn_fused<<<dim3(16, 64), 256, 0, stream>>>(QK, VT, yw);
  gemm_proj<<<dim3(64, 6), 256, 0, stream>>>(yw, wpb, bp_f, out,
                                             8192, 768, 768);
}

// Round 3
// 224.755 us; speedup vs baseline: 1.0255x; 1.0126x over previous
//
#include <hip/hip_runtime.h>
#include <hip/hip_bf16.h>
#include <stdint.h>

// GPT causal self-attention block. B=8, T=1024, C=768, H=8, D=96. f32 I/O.
// bf16 MFMA pipeline with fp32 accumulation. Causal mask input ignored.
//
// R2: counted-vmcnt pipelines (T4). Raw s_barrier (no compiler vmcnt(0)
// drain) + hand-counted s_waitcnt. GEMMs: 3-buffer 2-deep prefetch,
// vmcnt(4) steady-state. attn: K gloads stay in flight a full iteration
// (vmcnt(3) counted against next V reg-loads). GEMM LDS reads bank-swizzled
// (T2 both-sides: pre-swizzled global source + swizzled ds_read slot).

typedef unsigned short ushort_t;
typedef __attribute__((ext_vector_type(8))) short short8;     // 8 bf16 = 4 VGPRs
typedef __attribute__((ext_vector_type(4))) float floatx4;    // MFMA C/D frag
typedef __attribute__((ext_vector_type(4))) unsigned short ushort4v;

#define MFMA16(a, b, c) __builtin_amdgcn_mfma_f32_16x16x32_bf16(a, b, c, 0, 0, 0)
#define NEG_BIG (-1e30f)

__device__ __forceinline__ unsigned short f2bf(float f) {
  union { float f; unsigned int u; } v; v.f = f;
  unsigned int r = (v.u + 0x7FFFu + ((v.u >> 16) & 1u)) >> 16;  // RNE
  return (unsigned short)r;
}

__device__ __forceinline__ unsigned int packbf2(float a, float b) {
  // low 16 = bf16(a), high 16 = bf16(b)  (v_cvt_pk_bf16_f32)
  union { __hip_bfloat162 h; unsigned int u; } cv;
  cv.h = __float22bfloat162_rn(make_float2(a, b));
  return cv.u;
}

#define GLOAD16(src, dst)                                              \
  __builtin_amdgcn_global_load_lds(                                    \
      (const __attribute__((address_space(1))) void*)(src),            \
      (__attribute__((address_space(3))) void*)(dst), 16, 0, 0)

// counted wait + raw barrier (no vmcnt(0) auto-drain like __syncthreads)
#define WAITBAR(VM)                                                    \
  do {                                                                 \
    asm volatile("s_waitcnt vmcnt(" #VM ")" ::: "memory");             \
    __builtin_amdgcn_sched_barrier(0);                                 \
    __builtin_amdgcn_s_barrier();                                      \
    __builtin_amdgcn_sched_barrier(0);                                 \
  } while (0)

#define WAITBAR_LGKM(VM)                                               \
  do {                                                                 \
    asm volatile("s_waitcnt vmcnt(" #VM ") lgkmcnt(0)" ::: "memory");  \
    __builtin_amdgcn_sched_barrier(0);                                 \
    __builtin_amdgcn_s_barrier();                                      \
    __builtin_amdgcn_sched_barrier(0);                                 \
  } while (0)

// ---------------------------------------------------------------------------
// Fused f32->bf16 conversion for x, Wqkv, Wproj in one launch.
// ---------------------------------------------------------------------------
__global__ __launch_bounds__(256) void cvt3(
    const float* __restrict__ x, const float* __restrict__ wa,
    const float* __restrict__ wp, ushort_t* __restrict__ xb,
    ushort_t* __restrict__ wab, ushort_t* __restrict__ wpb)
{
  const int n1 = (8192 * 768) / 4, n2 = (2304 * 768) / 4;
  int i = blockIdx.x * 256 + threadIdx.x;
  const float* in; ushort_t* out;
  if (i < n1)            { in = x;  out = xb; }
  else if (i < n1 + n2)  { in = wa; out = wab; i -= n1; }
  else                   { in = wp; out = wpb; i -= (n1 + n2); }
  float4 v = *(const float4*)(in + (size_t)i * 4);
  ushort4v o;
  o.x = f2bf(v.x); o.y = f2bf(v.y); o.z = f2bf(v.z); o.w = f2bf(v.w);
  *(ushort4v*)(out + (size_t)i * 4) = o;
}

// ---------------------------------------------------------------------------
// Shared GEMM machinery: 128x128 tile, BK=32, 4 waves 2x2, 3-buffer LDS,
// 2-deep prefetch with counted vmcnt(4). K = 768 (24 K-steps) fixed.
// Bank swizzle: physical 16B slot = quad ^ ((row ^ row>>2) & 3), realized by
// pre-swizzling the GLOBAL source column (LDS dest must stay linear for
// global_load_lds) and reading with the same XOR.
// ---------------------------------------------------------------------------
#define GEMM_STAGE(BUF, OFF)                                           \
  do {                                                                 \
    ushort_t* lA = &As[BUF][wid * 512];                                \
    ushort_t* lB = &Bs[BUF][wid * 512];                                \
    const ushort_t* pA = gA + (OFF);                                   \
    const ushort_t* pB = gB + (OFF);                                   \
    GLOAD16(pA, lA);                                                   \
    GLOAD16(pA + (size_t)64 * 768, lA + 64 * 32);                      \
    GLOAD16(pB, lB);                                                   \
    GLOAD16(pB + (size_t)64 * 768, lB + 64 * 32);                      \
  } while (0)

#define GEMM_COMPUTE(BUF)                                              \
  do {                                                                 \
    short8 af[4], bf[4];                                               \
    _Pragma("unroll")                                                  \
    for (int t_ = 0; t_ < 4; ++t_) {                                   \
      af[t_] = *(const short8*)&As[BUF][(wm + t_ * 16 + l15) * 32 + sw]; \
      bf[t_] = *(const short8*)&Bs[BUF][(wn + t_ * 16 + l15) * 32 + sw]; \
    }                                                                  \
    _Pragma("unroll")                                                  \
    for (int tm = 0; tm < 4; ++tm)                                     \
      _Pragma("unroll")                                                \
      for (int tn = 0; tn < 4; ++tn)                                   \
        acc[tm][tn] = MFMA16(af[tm], bf[tn], acc[tm][tn]);             \
  } while (0)

// ---------------------------------------------------------------------------
// QKV GEMM: qkv = x @ Wqkv^T + b. Q columns pre-scaled by (1/sqrt(96))*log2e.
// Writes q,k into QK (row stride 1536) and v TRANSPOSED into VT[b][h][d][T]
// with time index sigma-permuted within each 64-block (attention needs no
// cross-lane P exchange).
// ---------------------------------------------------------------------------
__global__ __launch_bounds__(256) void gemm_qkv(
    const ushort_t* __restrict__ A,   // 8192 x 768 bf16 (x)
    const ushort_t* __restrict__ W,   // 2304 x 768 bf16
    const float* __restrict__ bias,   // 2304 f32
    ushort_t* __restrict__ QK,        // 8192 x 1536 bf16
    ushort_t* __restrict__ VT)        // (64 bh) x 96 x 1024 bf16 (perm cols)
{
  const int K = 768;
  __shared__ ushort_t As[3][128 * 32];
  __shared__ ushort_t Bs[3][128 * 32];

  const int tid  = threadIdx.x;
  const int lane = tid & 63;
  const int l15  = lane & 15;
  const int quad = lane >> 4;
  const int wid  = tid >> 6;
  const int m0 = blockIdx.x * 128;
  const int n0 = blockIdx.y * 128;
  const int wm = (wid >> 1) * 64;
  const int wn = (wid & 1) * 64;
  const int srow = tid >> 2;
  // pre-swizzled global source column for this thread's physical 16B slot
  const int scol = (((tid & 3) ^ ((srow ^ (srow >> 2)) & 3))) * 8;
  // swizzled read slot (element offset) for fragment loads
  const int sw = (quad ^ ((l15 ^ (l15 >> 2)) & 3)) * 8;

  floatx4 acc[4][4] = {};

  const ushort_t* gA = A + (size_t)(m0 + srow) * K + scol;
  const ushort_t* gB = W + (size_t)(n0 + srow) * K + scol;

  GEMM_STAGE(0, 0);
  GEMM_STAGE(1, 32);

  int bc = 0;  // buffer holding tile t
  for (int t = 0; t < 24; ++t) {
    if (t < 23) WAITBAR(4); else WAITBAR(0);
    if (t + 2 < 24) {
      const int bs = (bc >= 1) ? bc - 1 : 2;   // (t+2)%3
      GEMM_STAGE(bs, (t + 2) * 32);
    }
    GEMM_COMPUTE(bc);
    bc = (bc < 2) ? bc + 1 : 0;
  }

  const float QSCALE = 0.10206207261596577f * 1.4426950408889634f;

#pragma unroll
  for (int tn = 0; tn < 4; ++tn) {
    const int gc = n0 + wn + tn * 16 + l15;
    const float bv = bias[gc];
    const bool isv = (gc >= 1536);          // whole 16-col tile same side
    const bool isq = (gc < 768);
    const int hh = (gc - 1536) / 96, dd = (gc - 1536) % 96;
#pragma unroll
    for (int tm = 0; tm < 4; ++tm) {
      const int gr = m0 + wm + tm * 16 + quad * 4;
#pragma unroll
      for (int r = 0; r < 4; ++r) {
        float val = acc[tm][tn][r] + bv;
        const int row = gr + r;
        if (!isv) {
          if (isq) val *= QSCALE;
          QK[(size_t)row * 1536 + gc] = f2bf(val);
        } else {
          const int bb = row >> 10, tt = row & 1023;
          // sigma: bit2 <- tt.bit4, bits4..3 <- tt.bits3..2
          const int tt2 = (tt & ~0x1C) | (((tt >> 4) & 1) << 2) |
                          (((tt >> 2) & 3) << 3);
          VT[(((size_t)(bb * 8 + hh)) * 96 + dd) * 1024 + tt2] = f2bf(val);
        }
      }
    }
  }
}

// ---------------------------------------------------------------------------
// Generic GEMM (proj): C[m][n] = sum_k A[m][k] W[n][k] + bias[n], f32 out.
// K must be 768 (asserted by launch). Same counted pipeline.
// ---------------------------------------------------------------------------
__global__ __launch_bounds__(256) void gemm_proj(
    const ushort_t* __restrict__ A,   // M x 768 bf16
    const ushort_t* __restrict__ W,   // N x 768 bf16
    const float* __restrict__ bias,   // N f32
    float* __restrict__ C,            // M x N f32
    int M, int N)
{
  const int K = 768;
  __shared__ ushort_t As[3][128 * 32];
  __shared__ ushort_t Bs[3][128 * 32];

  const int tid  = threadIdx.x;
  const int lane = tid & 63;
  const int l15  = lane & 15;
  const int quad = lane >> 4;
  const int wid  = tid >> 6;
  const int m0 = blockIdx.x * 128;
  const int n0 = blockIdx.y * 128;
  const int wm = (wid >> 1) * 64;
  const int wn = (wid & 1) * 64;
  const int srow = tid >> 2;
  const int scol = (((tid & 3) ^ ((srow ^ (srow >> 2)) & 3))) * 8;
  const int sw = (quad ^ ((l15 ^ (l15 >> 2)) & 3)) * 8;

  floatx4 acc[4][4] = {};

  const ushort_t* gA = A + (size_t)(m0 + srow) * K + scol;
  const ushort_t* gB = W + (size_t)(n0 + srow) * K + scol;

  GEMM_STAGE(0, 0);
  GEMM_STAGE(1, 32);

  int bc = 0;
  for (int t = 0; t < 24; ++t) {
    if (t < 23) WAITBAR(4); else WAITBAR(0);
    if (t + 2 < 24) {
      const int bs = (bc >= 1) ? bc - 1 : 2;   // (t+2)%3
      GEMM_STAGE(bs, (t + 2) * 32);
    }
    GEMM_COMPUTE(bc);
    bc = (bc < 2) ? bc + 1 : 0;
  }

#pragma unroll
  for (int tn = 0; tn < 4; ++tn) {
    const int gc = n0 + wn + tn * 16 + l15;
    const float bv = bias[gc];
#pragma unroll
    for (int tm = 0; tm < 4; ++tm) {
      const int gr = m0 + wm + tm * 16 + quad * 4;
#pragma unroll
      for (int r = 0; r < 4; ++r)
        C[(size_t)(gr + r) * N + gc] = acc[tm][tn][r] + bv;
    }
  }
}

// ---------------------------------------------------------------------------
// Fused causal flash attention, swapped-QK^T form, counted-vmcnt pipeline.
// Grid (16, 64): block = (b,h) + paired q-chunks cA=bx, cB=31-bx (32 rows ea).
// Waves 0,1 -> chunk A rows; waves 2,3 -> chunk B rows (16 q-rows per wave).
// BK=64 keys/tile. Per iter t: {wait vmcnt(3)+lgkm; barrier; issue K(t+1)
// gloads; compute(t); ds_write V(t+1) (auto counted wait keeps K in flight);
// issue V(t+2) reg loads}. K gloads get a full iteration to land.
// ---------------------------------------------------------------------------
__global__ __launch_bounds__(256) void attn_fused(
    const ushort_t* __restrict__ QK,   // (B*T) x 1536 bf16  [q*scale | k]
    const ushort_t* __restrict__ VT,   // (64 bh) x 96 x 1024 bf16 (perm cols)
    ushort_t* __restrict__ y)          // (B*T) x 768 bf16
{
  __shared__ ushort_t Ks[2][64 * 96];  // packed: global_load_lds target
  __shared__ ushort_t Vt[2][96 * 72];  // padded rows (72) for b128 reads

  const int tid  = threadIdx.x;
  const int lane = tid & 63;
  const int l15  = lane & 15;
  const int quad = lane >> 4;
  const int wid  = tid >> 6;
  const int bh = blockIdx.y;
  const int b = bh >> 3;
  const int h = bh & 7;
  const int qoff = h * 96;

  const int cA = blockIdx.x;           // 0..15
  const int cB = 31 - cA;              // 16..31
  const int myChunk = (wid < 2) ? cA : cB;
  const int q0w = myChunk * 32 + (wid & 1) * 16;   // wave's first q row
  const int kend = cB * 32 + 32;                   // loop bound (chunk B)
  const int rq = q0w + l15;                        // this lane's q row

  const size_t rowbase = (size_t)b * 1024;
  const ushort_t* vtb = VT + (size_t)bh * 96 * 1024;

  // per-thread staging coords
  const int ke0 = wid * 1536 + lane * 8;           // K-stage element base
  const int vd  = (tid >> 3);                      // V-stage row within group
  const int vkc = (tid & 7) * 8;                   // V-stage col

  // Q fragments (used as B operand), K=96 in 3 chunks of 32
  short8 qf[3];
#pragma unroll
  for (int c = 0; c < 3; ++c)
    qf[c] = *(const short8*)(QK + (rowbase + q0w + l15) * 1536 + qoff +
                             c * 32 + quad * 8);

  float m_i = NEG_BIG;   // running max for row l15 (exp2 domain)
  float l_i = 0.f;       // running denom for row l15
  floatx4 O[6] = {};

  short8 vreg[3];

  // prologue: V(0) regs FIRST (so later use-wait leaves K(0) in flight),
  // then K(0) gloads, write V(0), then issue V(1) regs.
#pragma unroll
  for (int g = 0; g < 3; ++g)
    vreg[g] = *(const short8*)(vtb + (size_t)(g * 32 + vd) * 1024 + vkc);
#pragma unroll
  for (int i = 0; i < 3; ++i) {
    const int e = ke0 + i * 512;
    const int kr = e / 96, kc = e % 96;
    GLOAD16(QK + (rowbase + kr) * 1536 + 768 + qoff + kc,
            &Ks[0][wid * 1536 + i * 512]);
  }
#pragma unroll
  for (int g = 0; g < 3; ++g)
    *(short8*)&Vt[0][(g * 32 + vd) * 72 + vkc] = vreg[g];
#pragma unroll
  for (int g = 0; g < 3; ++g)
    vreg[g] = *(const short8*)(vtb + (size_t)(g * 32 + vd) * 1024 + 64 + vkc);

  int cur = 0;
  for (int k0 = 0; k0 < kend; k0 += 64) {
    const int nk = k0 + 64;
    const bool more = (nk < kend);

    // wait: K(t) gloads done (3 newest allowed = V(t+1) regs), LDS writes
    // from previous iteration flushed; then converge.
    if (more) WAITBAR_LGKM(3); else WAITBAR_LGKM(0);

    // issue K(t+1) gloads early (a full iteration to land)
    if (more) {
#pragma unroll
      for (int i = 0; i < 3; ++i) {
        const int e = ke0 + i * 512;
        const int kr = e / 96, kc = e % 96;
        GLOAD16(QK + (rowbase + nk + kr) * 1536 + 768 + qoff + kc,
                &Ks[cur ^ 1][wid * 1536 + i * 512]);
      }
    }

    if (k0 < q0w + 16) {  // wave-uniform activity test
      // QK^T swapped: s[t] = K_tile(t) * Q  -> rows=keys, cols=q
      floatx4 s[4] = {};
#pragma unroll
      for (int t = 0; t < 4; ++t) {
#pragma unroll
        for (int c = 0; c < 3; ++c) {
          short8 kf = *(const short8*)
              &Ks[cur][(t * 16 + l15) * 96 + c * 32 + quad * 8];
          s[t] = MFMA16(kf, qf[c], s[t]);
        }
      }
      // scores for row rq: key = k0 + t*16 + quad*4 + j
      float p[4][4];
      if (k0 + 64 <= q0w) {            // fully unmasked tile (fast path)
#pragma unroll
        for (int t = 0; t < 4; ++t)
#pragma unroll
          for (int j = 0; j < 4; ++j) p[t][j] = s[t][j];
      } else {                          // diagonal tile: causal mask
        const int kq = k0 + quad * 4;
#pragma unroll
        for (int t = 0; t < 4; ++t)
#pragma unroll
          for (int j = 0; j < 4; ++j)
            p[t][j] = (kq + t * 16 + j <= rq) ? s[t][j] : NEG_BIG;
      }
      // row max: in-lane tree (16) + cross-quad
      float m0v = fmaxf(fmaxf(p[0][0], p[0][1]), fmaxf(p[0][2], p[0][3]));
      float m1v = fmaxf(fmaxf(p[1][0], p[1][1]), fmaxf(p[1][2], p[1][3]));
      float m2v = fmaxf(fmaxf(p[2][0], p[2][1]), fmaxf(p[2][2], p[2][3]));
      float m3v = fmaxf(fmaxf(p[3][0], p[3][1]), fmaxf(p[3][2], p[3][3]));
      float mt = fmaxf(fmaxf(m0v, m1v), fmaxf(m2v, m3v));
      mt = fmaxf(mt, __shfl_xor(mt, 16));
      mt = fmaxf(mt, __shfl_xor(mt, 32));
      // defer-max: only rescale when max grew by > 8 (exp2 headroom 2^8)
      if (!__all(mt - m_i <= 8.0f)) {
        const float mn = fmaxf(m_i, mt);
        const float al = __builtin_amdgcn_exp2f(m_i - mn);
        m_i = mn;
        l_i *= al;
#pragma unroll
        for (int j = 0; j < 4; ++j) {
          const float alr = __shfl(al, quad * 4 + j);  // al of O-row quad*4+j
#pragma unroll
          for (int f = 0; f < 6; ++f) O[f][j] *= alr;
        }
      }
      float rs = 0.f;
#pragma unroll
      for (int t = 0; t < 4; ++t)
#pragma unroll
        for (int j = 0; j < 4; ++j) {
          p[t][j] = __builtin_amdgcn_exp2f(p[t][j] - m_i);
          rs += p[t][j];
        }
      rs += __shfl_xor(rs, 16);
      rs += __shfl_xor(rs, 32);
      l_i += rs;
      // pack P to bf16 A-frags entirely in-lane (keys pre-permuted into V)
      union { short8 s8; unsigned int u[4]; } pf0, pf1;
      pf0.u[0] = packbf2(p[0][0], p[0][1]);
      pf0.u[1] = packbf2(p[0][2], p[0][3]);
      pf0.u[2] = packbf2(p[1][0], p[1][1]);
      pf0.u[3] = packbf2(p[1][2], p[1][3]);
      pf1.u[0] = packbf2(p[2][0], p[2][1]);
      pf1.u[1] = packbf2(p[2][2], p[2][3]);
      pf1.u[2] = packbf2(p[3][0], p[3][1]);
      pf1.u[3] = packbf2(p[3][2], p[3][3]);
#pragma unroll
      for (int f = 0; f < 6; ++f) {
        short8 vf0 = *(const short8*)&Vt[cur][(f * 16 + l15) * 72 + quad * 8];
        O[f] = MFMA16(pf0.s8, vf0, O[f]);
        short8 vf1 = *(const short8*)
            &Vt[cur][(f * 16 + l15) * 72 + 32 + quad * 8];
        O[f] = MFMA16(pf1.s8, vf1, O[f]);
      }
    }

    if (more) {
      // write-late: V(t+1) regs -> LDS (auto-wait is counted: K(t+1) gloads
      // are newer than these regs, so they stay in flight)
#pragma unroll
      for (int g = 0; g < 3; ++g)
        *(short8*)&Vt[cur ^ 1][(g * 32 + vd) * 72 + vkc] = vreg[g];
      // issue V(t+2) reg loads (newest outstanding -> counted waits work)
      if (nk + 64 < kend) {
#pragma unroll
        for (int g = 0; g < 3; ++g)
          vreg[g] = *(const short8*)
              (vtb + (size_t)(g * 32 + vd) * 1024 + nk + 64 + vkc);
      }
    }
    cur ^= 1;
  }

  // epilogue: O rows are quad*4+j; softmax denom lives in lane (row)
  float inv[4];
#pragma unroll
  for (int j = 0; j < 4; ++j) {
    const float lj = __shfl(l_i, quad * 4 + j);
    inv[j] = 1.0f / fmaxf(lj, 1e-20f);
  }
#pragma unroll
  for (int j = 0; j < 4; ++j) {
    const size_t row = rowbase + q0w + quad * 4 + j;
#pragma unroll
    for (int f = 0; f < 6; ++f)
      y[row * 768 + qoff + f * 16 + l15] = f2bf(O[f][j] * inv[j]);
  }
}

// ---------------------------------------------------------------------------
extern "C" void kernel_launch(void* const* d_in, const int* in_sizes, int n_in,
                              void* d_out, int out_size, void* d_ws, size_t ws_size,
                              hipStream_t stream)
{
  const float* x_f  = (const float*)d_in[0];
  const float* wa_f = (const float*)d_in[1];
  const float* ba_f = (const float*)d_in[2];
  const float* wp_f = (const float*)d_in[3];
  const float* bp_f = (const float*)d_in[4];
  float* out = (float*)d_out;

  ushort_t* xb  = (ushort_t*)d_ws;                    // 8192 x  768
  ushort_t* wab = xb  + (size_t)8192 * 768;           // 2304 x  768
  ushort_t* wpb = wab + (size_t)2304 * 768;           //  768 x  768
  ushort_t* QK  = wpb + (size_t)768 * 768;            // 8192 x 1536
  ushort_t* VT  = QK  + (size_t)8192 * 1536;          // 64 x 96 x 1024
  ushort_t* yw  = VT  + (size_t)8192 * 768;           // 8192 x  768

  // (8192*768 + 2304*768 + 768*768)/4 = 2162688 = 8448 * 256
  cvt3<<<8448, 256, 0, stream>>>(x_f, wa_f, wp_f, xb, wab, wpb);

  gemm_qkv<<<dim3(64, 18), 256, 0, stream>>>(xb, wab, ba_f, QK, VT);
  attn_fused<<<dim3(16, 64), 256, 0, stream>>>(QK, VT, yw);
  gemm_proj<<<dim3(64, 6), 256, 0, stream>>>(yw, wpb, bp_f, out,
                                             8192, 768);
}

// Round 4
// 220.637 us; speedup vs baseline: 1.0446x; 1.0187x over previous
//
#include <hip/hip_runtime.h>
#include <hip/hip_bf16.h>
#include <stdint.h>

// GPT causal self-attention block. B=8, T=1024, C=768, H=8, D=96. f32 I/O.
// bf16 MFMA pipeline with fp32 accumulation. Causal mask input ignored.
//
// R3: remove sched_barrier(0) pins from the counted-vmcnt pipeline (m141:
// order-pinning defeats the compiler scheduler, up to -40%). Keep asm
// "memory" clobbers on counted s_waitcnt for correctness. Add s_setprio(1)
// around MFMA clusters (T5; phase-split schedule now exists). Fully unroll
// the GEMM K-loop so 3-buffer rotation is compile-time static.

typedef unsigned short ushort_t;
typedef __attribute__((ext_vector_type(8))) short short8;     // 8 bf16 = 4 VGPRs
typedef __attribute__((ext_vector_type(4))) float floatx4;    // MFMA C/D frag
typedef __attribute__((ext_vector_type(4))) unsigned short ushort4v;

#define MFMA16(a, b, c) __builtin_amdgcn_mfma_f32_16x16x32_bf16(a, b, c, 0, 0, 0)
#define NEG_BIG (-1e30f)

__device__ __forceinline__ unsigned short f2bf(float f) {
  union { float f; unsigned int u; } v; v.f = f;
  unsigned int r = (v.u + 0x7FFFu + ((v.u >> 16) & 1u)) >> 16;  // RNE
  return (unsigned short)r;
}

__device__ __forceinline__ unsigned int packbf2(float a, float b) {
  // low 16 = bf16(a), high 16 = bf16(b)  (v_cvt_pk_bf16_f32)
  union { __hip_bfloat162 h; unsigned int u; } cv;
  cv.h = __float22bfloat162_rn(make_float2(a, b));
  return cv.u;
}

#define GLOAD16(src, dst)                                              \
  __builtin_amdgcn_global_load_lds(                                    \
      (const __attribute__((address_space(1))) void*)(src),            \
      (__attribute__((address_space(3))) void*)(dst), 16, 0, 0)

// counted wait + raw barrier. The asm "memory" clobber orders all memory
// ops (ds_read/ds_write/global_load_lds) across the wait+barrier; NO
// sched_barrier pins (m141: pinning defeats compiler scheduling).
#define WAITBAR(VM)                                                    \
  do {                                                                 \
    asm volatile("s_waitcnt vmcnt(" #VM ")" ::: "memory");             \
    __builtin_amdgcn_s_barrier();                                      \
  } while (0)

#define WAITBAR_LGKM(VM)                                               \
  do {                                                                 \
    asm volatile("s_waitcnt vmcnt(" #VM ") lgkmcnt(0)" ::: "memory");  \
    __builtin_amdgcn_s_barrier();                                      \
  } while (0)

// ---------------------------------------------------------------------------
// Fused f32->bf16 conversion for x, Wqkv, Wproj in one launch.
// ---------------------------------------------------------------------------
__global__ __launch_bounds__(256) void cvt3(
    const float* __restrict__ x, const float* __restrict__ wa,
    const float* __restrict__ wp, ushort_t* __restrict__ xb,
    ushort_t* __restrict__ wab, ushort_t* __restrict__ wpb)
{
  const int n1 = (8192 * 768) / 4, n2 = (2304 * 768) / 4;
  int i = blockIdx.x * 256 + threadIdx.x;
  const float* in; ushort_t* out;
  if (i < n1)            { in = x;  out = xb; }
  else if (i < n1 + n2)  { in = wa; out = wab; i -= n1; }
  else                   { in = wp; out = wpb; i -= (n1 + n2); }
  float4 v = *(const float4*)(in + (size_t)i * 4);
  ushort4v o;
  o.x = f2bf(v.x); o.y = f2bf(v.y); o.z = f2bf(v.z); o.w = f2bf(v.w);
  *(ushort4v*)(out + (size_t)i * 4) = o;
}

// ---------------------------------------------------------------------------
// Shared GEMM machinery: 128x128 tile, BK=32, 4 waves 2x2, 3-buffer LDS,
// 2-deep prefetch with counted vmcnt(4). K = 768 (24 K-steps) fixed.
// K-loop fully unrolled: buffer indices are compile-time constants.
// ---------------------------------------------------------------------------
#define GEMM_STAGE(BUF, OFF)                                           \
  do {                                                                 \
    ushort_t* lA = &As[BUF][wid * 512];                                \
    ushort_t* lB = &Bs[BUF][wid * 512];                                \
    const ushort_t* pA = gA + (OFF);                                   \
    const ushort_t* pB = gB + (OFF);                                   \
    GLOAD16(pA, lA);                                                   \
    GLOAD16(pA + (size_t)64 * 768, lA + 64 * 32);                      \
    GLOAD16(pB, lB);                                                   \
    GLOAD16(pB + (size_t)64 * 768, lB + 64 * 32);                      \
  } while (0)

#define GEMM_COMPUTE(BUF)                                              \
  do {                                                                 \
    short8 af[4], bf[4];                                               \
    _Pragma("unroll")                                                  \
    for (int t_ = 0; t_ < 4; ++t_) {                                   \
      af[t_] = *(const short8*)&As[BUF][(wm + t_ * 16 + l15) * 32 + sw]; \
      bf[t_] = *(const short8*)&Bs[BUF][(wn + t_ * 16 + l15) * 32 + sw]; \
    }                                                                  \
    __builtin_amdgcn_s_setprio(1);                                     \
    _Pragma("unroll")                                                  \
    for (int tm = 0; tm < 4; ++tm)                                     \
      _Pragma("unroll")                                                \
      for (int tn = 0; tn < 4; ++tn)                                   \
        acc[tm][tn] = MFMA16(af[tm], bf[tn], acc[tm][tn]);             \
    __builtin_amdgcn_s_setprio(0);                                     \
  } while (0)

#define GEMM_KLOOP                                                     \
  do {                                                                 \
    GEMM_STAGE(0, 0);                                                  \
    GEMM_STAGE(1, 32);                                                 \
    _Pragma("unroll")                                                  \
    for (int t = 0; t < 24; ++t) {                                     \
      if (t < 23) WAITBAR(4); else WAITBAR(0);                         \
      if (t + 2 < 24) GEMM_STAGE((t + 2) % 3, (t + 2) * 32);           \
      GEMM_COMPUTE(t % 3);                                             \
    }                                                                  \
  } while (0)

// ---------------------------------------------------------------------------
// QKV GEMM: qkv = x @ Wqkv^T + b. Q columns pre-scaled by (1/sqrt(96))*log2e.
// Writes q,k into QK (row stride 1536) and v TRANSPOSED into VT[b][h][d][T]
// with time index sigma-permuted within each 64-block (attention needs no
// cross-lane P exchange).
// ---------------------------------------------------------------------------
__global__ __launch_bounds__(256) void gemm_qkv(
    const ushort_t* __restrict__ A,   // 8192 x 768 bf16 (x)
    const ushort_t* __restrict__ W,   // 2304 x 768 bf16
    const float* __restrict__ bias,   // 2304 f32
    ushort_t* __restrict__ QK,        // 8192 x 1536 bf16
    ushort_t* __restrict__ VT)        // (64 bh) x 96 x 1024 bf16 (perm cols)
{
  const int K = 768;
  __shared__ ushort_t As[3][128 * 32];
  __shared__ ushort_t Bs[3][128 * 32];

  const int tid  = threadIdx.x;
  const int lane = tid & 63;
  const int l15  = lane & 15;
  const int quad = lane >> 4;
  const int wid  = tid >> 6;
  const int m0 = blockIdx.x * 128;
  const int n0 = blockIdx.y * 128;
  const int wm = (wid >> 1) * 64;
  const int wn = (wid & 1) * 64;
  const int srow = tid >> 2;
  // pre-swizzled global source column for this thread's physical 16B slot
  const int scol = (((tid & 3) ^ ((srow ^ (srow >> 2)) & 3))) * 8;
  // swizzled read slot (element offset) for fragment loads
  const int sw = (quad ^ ((l15 ^ (l15 >> 2)) & 3)) * 8;

  floatx4 acc[4][4] = {};

  const ushort_t* gA = A + (size_t)(m0 + srow) * K + scol;
  const ushort_t* gB = W + (size_t)(n0 + srow) * K + scol;

  GEMM_KLOOP;

  const float QSCALE = 0.10206207261596577f * 1.4426950408889634f;

#pragma unroll
  for (int tn = 0; tn < 4; ++tn) {
    const int gc = n0 + wn + tn * 16 + l15;
    const float bv = bias[gc];
    const bool isv = (gc >= 1536);          // whole 16-col tile same side
    const bool isq = (gc < 768);
    const int hh = (gc - 1536) / 96, dd = (gc - 1536) % 96;
#pragma unroll
    for (int tm = 0; tm < 4; ++tm) {
      const int gr = m0 + wm + tm * 16 + quad * 4;
#pragma unroll
      for (int r = 0; r < 4; ++r) {
        float val = acc[tm][tn][r] + bv;
        const int row = gr + r;
        if (!isv) {
          if (isq) val *= QSCALE;
          QK[(size_t)row * 1536 + gc] = f2bf(val);
        } else {
          const int bb = row >> 10, tt = row & 1023;
          // sigma: bit2 <- tt.bit4, bits4..3 <- tt.bits3..2
          const int tt2 = (tt & ~0x1C) | (((tt >> 4) & 1) << 2) |
                          (((tt >> 2) & 3) << 3);
          VT[(((size_t)(bb * 8 + hh)) * 96 + dd) * 1024 + tt2] = f2bf(val);
        }
      }
    }
  }
}

// ---------------------------------------------------------------------------
// Generic GEMM (proj): C[m][n] = sum_k A[m][k] W[n][k] + bias[n], f32 out.
// K = 768 fixed. Same counted pipeline.
// ---------------------------------------------------------------------------
__global__ __launch_bounds__(256) void gemm_proj(
    const ushort_t* __restrict__ A,   // M x 768 bf16
    const ushort_t* __restrict__ W,   // N x 768 bf16
    const float* __restrict__ bias,   // N f32
    float* __restrict__ C,            // M x N f32
    int M, int N)
{
  const int K = 768;
  __shared__ ushort_t As[3][128 * 32];
  __shared__ ushort_t Bs[3][128 * 32];

  const int tid  = threadIdx.x;
  const int lane = tid & 63;
  const int l15  = lane & 15;
  const int quad = lane >> 4;
  const int wid  = tid >> 6;
  const int m0 = blockIdx.x * 128;
  const int n0 = blockIdx.y * 128;
  const int wm = (wid >> 1) * 64;
  const int wn = (wid & 1) * 64;
  const int srow = tid >> 2;
  const int scol = (((tid & 3) ^ ((srow ^ (srow >> 2)) & 3))) * 8;
  const int sw = (quad ^ ((l15 ^ (l15 >> 2)) & 3)) * 8;

  floatx4 acc[4][4] = {};

  const ushort_t* gA = A + (size_t)(m0 + srow) * K + scol;
  const ushort_t* gB = W + (size_t)(n0 + srow) * K + scol;

  GEMM_KLOOP;

#pragma unroll
  for (int tn = 0; tn < 4; ++tn) {
    const int gc = n0 + wn + tn * 16 + l15;
    const float bv = bias[gc];
#pragma unroll
    for (int tm = 0; tm < 4; ++tm) {
      const int gr = m0 + wm + tm * 16 + quad * 4;
#pragma unroll
      for (int r = 0; r < 4; ++r)
        C[(size_t)(gr + r) * N + gc] = acc[tm][tn][r] + bv;
    }
  }
}

// ---------------------------------------------------------------------------
// Fused causal flash attention, swapped-QK^T form, counted-vmcnt pipeline.
// Grid (16, 64): block = (b,h) + paired q-chunks cA=bx, cB=31-cA (32 rows ea).
// Waves 0,1 -> chunk A rows; waves 2,3 -> chunk B rows (16 q-rows per wave).
// BK=64 keys/tile. Per iter t: {wait vmcnt(3)+lgkm; barrier; issue K(t+1)
// gloads; compute(t); ds_write V(t+1); issue V(t+2) reg loads}.
// ---------------------------------------------------------------------------
__global__ __launch_bounds__(256) void attn_fused(
    const ushort_t* __restrict__ QK,   // (B*T) x 1536 bf16  [q*scale | k]
    const ushort_t* __restrict__ VT,   // (64 bh) x 96 x 1024 bf16 (perm cols)
    ushort_t* __restrict__ y)          // (B*T) x 768 bf16
{
  __shared__ ushort_t Ks[2][64 * 96];  // packed: global_load_lds target
  __shared__ ushort_t Vt[2][96 * 72];  // padded rows (72) for b128 reads

  const int tid  = threadIdx.x;
  const int lane = tid & 63;
  const int l15  = lane & 15;
  const int quad = lane >> 4;
  const int wid  = tid >> 6;
  const int bh = blockIdx.y;
  const int b = bh >> 3;
  const int h = bh & 7;
  const int qoff = h * 96;

  const int cA = blockIdx.x;           // 0..15
  const int cB = 31 - cA;              // 16..31
  const int myChunk = (wid < 2) ? cA : cB;
  const int q0w = myChunk * 32 + (wid & 1) * 16;   // wave's first q row
  const int kend = cB * 32 + 32;                   // loop bound (chunk B)
  const int rq = q0w + l15;                        // this lane's q row

  const size_t rowbase = (size_t)b * 1024;
  const ushort_t* vtb = VT + (size_t)bh * 96 * 1024;

  // per-thread staging coords
  const int ke0 = wid * 1536 + lane * 8;           // K-stage element base
  const int vd  = (tid >> 3);                      // V-stage row within group
  const int vkc = (tid & 7) * 8;                   // V-stage col

  // Q fragments (used as B operand), K=96 in 3 chunks of 32
  short8 qf[3];
#pragma unroll
  for (int c = 0; c < 3; ++c)
    qf[c] = *(const short8*)(QK + (rowbase + q0w + l15) * 1536 + qoff +
                             c * 32 + quad * 8);

  float m_i = NEG_BIG;   // running max for row l15 (exp2 domain)
  float l_i = 0.f;       // running denom for row l15
  floatx4 O[6] = {};

  short8 vreg[3];

  // prologue: V(0) regs FIRST (so later use-wait leaves K(0) in flight),
  // then K(0) gloads, write V(0), then issue V(1) regs.
#pragma unroll
  for (int g = 0; g < 3; ++g)
    vreg[g] = *(const short8*)(vtb + (size_t)(g * 32 + vd) * 1024 + vkc);
#pragma unroll
  for (int i = 0; i < 3; ++i) {
    const int e = ke0 + i * 512;
    const int kr = e / 96, kc = e % 96;
    GLOAD16(QK + (rowbase + kr) * 1536 + 768 + qoff + kc,
            &Ks[0][wid * 1536 + i * 512]);
  }
#pragma unroll
  for (int g = 0; g < 3; ++g)
    *(short8*)&Vt[0][(g * 32 + vd) * 72 + vkc] = vreg[g];
#pragma unroll
  for (int g = 0; g < 3; ++g)
    vreg[g] = *(const short8*)(vtb + (size_t)(g * 32 + vd) * 1024 + 64 + vkc);

  int cur = 0;
  for (int k0 = 0; k0 < kend; k0 += 64) {
    const int nk = k0 + 64;
    const bool more = (nk < kend);

    // wait: K(t) gloads done (3 newest allowed = V(t+1) regs), LDS writes
    // from previous iteration flushed; then converge.
    if (more) WAITBAR_LGKM(3); else WAITBAR_LGKM(0);

    // issue K(t+1) gloads early (a full iteration to land)
    if (more) {
#pragma unroll
      for (int i = 0; i < 3; ++i) {
        const int e = ke0 + i * 512;
        const int kr = e / 96, kc = e % 96;
        GLOAD16(QK + (rowbase + nk + kr) * 1536 + 768 + qoff + kc,
                &Ks[cur ^ 1][wid * 1536 + i * 512]);
      }
    }

    if (k0 < q0w + 16) {  // wave-uniform activity test
      // QK^T swapped: s[t] = K_tile(t) * Q  -> rows=keys, cols=q
      floatx4 s[4] = {};
      __builtin_amdgcn_s_setprio(1);
#pragma unroll
      for (int t = 0; t < 4; ++t) {
#pragma unroll
        for (int c = 0; c < 3; ++c) {
          short8 kf = *(const short8*)
              &Ks[cur][(t * 16 + l15) * 96 + c * 32 + quad * 8];
          s[t] = MFMA16(kf, qf[c], s[t]);
        }
      }
      __builtin_amdgcn_s_setprio(0);
      // scores for row rq: key = k0 + t*16 + quad*4 + j
      float p[4][4];
      if (k0 + 64 <= q0w) {            // fully unmasked tile (fast path)
#pragma unroll
        for (int t = 0; t < 4; ++t)
#pragma unroll
          for (int j = 0; j < 4; ++j) p[t][j] = s[t][j];
      } else {                          // diagonal tile: causal mask
        const int kq = k0 + quad * 4;
#pragma unroll
        for (int t = 0; t < 4; ++t)
#pragma unroll
          for (int j = 0; j < 4; ++j)
            p[t][j] = (kq + t * 16 + j <= rq) ? s[t][j] : NEG_BIG;
      }
      // row max: in-lane tree (16) + cross-quad
      float m0v = fmaxf(fmaxf(p[0][0], p[0][1]), fmaxf(p[0][2], p[0][3]));
      float m1v = fmaxf(fmaxf(p[1][0], p[1][1]), fmaxf(p[1][2], p[1][3]));
      float m2v = fmaxf(fmaxf(p[2][0], p[2][1]), fmaxf(p[2][2], p[2][3]));
      float m3v = fmaxf(fmaxf(p[3][0], p[3][1]), fmaxf(p[3][2], p[3][3]));
      float mt = fmaxf(fmaxf(m0v, m1v), fmaxf(m2v, m3v));
      mt = fmaxf(mt, __shfl_xor(mt, 16));
      mt = fmaxf(mt, __shfl_xor(mt, 32));
      // defer-max: only rescale when max grew by > 8 (exp2 headroom 2^8)
      if (!__all(mt - m_i <= 8.0f)) {
        const float mn = fmaxf(m_i, mt);
        const float al = __builtin_amdgcn_exp2f(m_i - mn);
        m_i = mn;
        l_i *= al;
#pragma unroll
        for (int j = 0; j < 4; ++j) {
          const float alr = __shfl(al, quad * 4 + j);  // al of O-row quad*4+j
#pragma unroll
          for (int f = 0; f < 6; ++f) O[f][j] *= alr;
        }
      }
      float rs = 0.f;
#pragma unroll
      for (int t = 0; t < 4; ++t)
#pragma unroll
        for (int j = 0; j < 4; ++j) {
          p[t][j] = __builtin_amdgcn_exp2f(p[t][j] - m_i);
          rs += p[t][j];
        }
      rs += __shfl_xor(rs, 16);
      rs += __shfl_xor(rs, 32);
      l_i += rs;
      // pack P to bf16 A-frags entirely in-lane (keys pre-permuted into V)
      union { short8 s8; unsigned int u[4]; } pf0, pf1;
      pf0.u[0] = packbf2(p[0][0], p[0][1]);
      pf0.u[1] = packbf2(p[0][2], p[0][3]);
      pf0.u[2] = packbf2(p[1][0], p[1][1]);
      pf0.u[3] = packbf2(p[1][2], p[1][3]);
      pf1.u[0] = packbf2(p[2][0], p[2][1]);
      pf1.u[1] = packbf2(p[2][2], p[2][3]);
      pf1.u[2] = packbf2(p[3][0], p[3][1]);
      pf1.u[3] = packbf2(p[3][2], p[3][3]);
      __builtin_amdgcn_s_setprio(1);
#pragma unroll
      for (int f = 0; f < 6; ++f) {
        short8 vf0 = *(const short8*)&Vt[cur][(f * 16 + l15) * 72 + quad * 8];
        O[f] = MFMA16(pf0.s8, vf0, O[f]);
        short8 vf1 = *(const short8*)
            &Vt[cur][(f * 16 + l15) * 72 + 32 + quad * 8];
        O[f] = MFMA16(pf1.s8, vf1, O[f]);
      }
      __builtin_amdgcn_s_setprio(0);
    }

    if (more) {
      // write-late: V(t+1) regs -> LDS (auto-wait is counted: K(t+1) gloads
      // are newer than these regs, so they stay in flight)
#pragma unroll
      for (int g = 0; g < 3; ++g)
        *(short8*)&Vt[cur ^ 1][(g * 32 + vd) * 72 + vkc] = vreg[g];
      // issue V(t+2) reg loads (newest outstanding -> counted waits work)
      if (nk + 64 < kend) {
#pragma unroll
        for (int g = 0; g < 3; ++g)
          vreg[g] = *(const short8*)
              (vtb + (size_t)(g * 32 + vd) * 1024 + nk + 64 + vkc);
      }
    }
    cur ^= 1;
  }

  // epilogue: O rows are quad*4+j; softmax denom lives in lane (row)
  float inv[4];
#pragma unroll
  for (int j = 0; j < 4; ++j) {
    const float lj = __shfl(l_i, quad * 4 + j);
    inv[j] = 1.0f / fmaxf(lj, 1e-20f);
  }
#pragma unroll
  for (int j = 0; j < 4; ++j) {
    const size_t row = rowbase + q0w + quad * 4 + j;
#pragma unroll
    for (int f = 0; f < 6; ++f)
      y[row * 768 + qoff + f * 16 + l15] = f2bf(O[f][j] * inv[j]);
  }
}

// ---------------------------------------------------------------------------
extern "C" void kernel_launch(void* const* d_in, const int* in_sizes, int n_in,
                              void* d_out, int out_size, void* d_ws, size_t ws_size,
                              hipStream_t stream)
{
  const float* x_f  = (const float*)d_in[0];
  const float* wa_f = (const float*)d_in[1];
  const float* ba_f = (const float*)d_in[2];
  const float* wp_f = (const float*)d_in[3];
  const float* bp_f = (const float*)d_in[4];
  float* out = (float*)d_out;

  ushort_t* xb  = (ushort_t*)d_ws;                    // 8192 x  768
  ushort_t* wab = xb  + (size_t)8192 * 768;           // 2304 x  768
  ushort_t* wpb = wab + (size_t)2304 * 768;           //  768 x  768
  ushort_t* QK  = wpb + (size_t)768 * 768;            // 8192 x 1536
  ushort_t* VT  = QK  + (size_t)8192 * 1536;          // 64 x 96 x 1024
  ushort_t* yw  = VT  + (size_t)8192 * 768;           // 8192 x  768

  // (8192*768 + 2304*768 + 768*768)/4 = 2162688 = 8448 * 256
  cvt3<<<8448, 256, 0, stream>>>(x_f, wa_f, wp_f, xb, wab, wpb);

  gemm_qkv<<<dim3(64, 18), 256, 0, stream>>>(xb, wab, ba_f, QK, VT);
  attn_fused<<<dim3(16, 64), 256, 0, stream>>>(QK, VT, yw);
  gemm_proj<<<dim3(64, 6), 256, 0, stream>>>(yw, wpb, bp_f, out,
                                             8192, 768);
}

// Round 5
// 215.504 us; speedup vs baseline: 1.0695x; 1.0238x over previous
//
#include <hip/hip_runtime.h>
#include <hip/hip_bf16.h>
#include <stdint.h>

// GPT causal self-attention block. B=8, T=1024, C=768, H=8, D=96. f32 I/O.
// bf16 MFMA pipeline with fp32 accumulation. Causal mask input ignored.
//
// R4: SEPARATE NAMED LDS BUFFERS. global_load_lds writes LDS through a
// pointer; with one array indexed [buf][...] the compiler must assume the
// staging write MayAlias the compute ds_reads and inserts its own
// s_waitcnt vmcnt(0) every iteration, silently defeating the counted-vmcnt
// pipeline. Distinct named __shared__ objects + compile-time buffer
// selection (static macro chains) make NoAlias provable.

typedef unsigned short ushort_t;
typedef __attribute__((ext_vector_type(8))) short short8;     // 8 bf16 = 4 VGPRs
typedef __attribute__((ext_vector_type(4))) float floatx4;    // MFMA C/D frag
typedef __attribute__((ext_vector_type(4))) unsigned short ushort4v;

#define MFMA16(a, b, c) __builtin_amdgcn_mfma_f32_16x16x32_bf16(a, b, c, 0, 0, 0)
#define NEG_BIG (-1e30f)

__device__ __forceinline__ unsigned short f2bf(float f) {
  union { float f; unsigned int u; } v; v.f = f;
  unsigned int r = (v.u + 0x7FFFu + ((v.u >> 16) & 1u)) >> 16;  // RNE
  return (unsigned short)r;
}

__device__ __forceinline__ unsigned int packbf2(float a, float b) {
  // low 16 = bf16(a), high 16 = bf16(b)  (v_cvt_pk_bf16_f32)
  union { __hip_bfloat162 h; unsigned int u; } cv;
  cv.h = __float22bfloat162_rn(make_float2(a, b));
  return cv.u;
}

#define GLOAD16(src, dst)                                              \
  __builtin_amdgcn_global_load_lds(                                    \
      (const __attribute__((address_space(1))) void*)(src),            \
      (__attribute__((address_space(3))) void*)(dst), 16, 0, 0)

// counted wait + raw barrier (no vmcnt(0) auto-drain like __syncthreads)
#define WAITBAR(VM)                                                    \
  do {                                                                 \
    asm volatile("s_waitcnt vmcnt(" #VM ")" ::: "memory");             \
    __builtin_amdgcn_s_barrier();                                      \
  } while (0)

#define WAITBAR_LGKM(VM)                                               \
  do {                                                                 \
    asm volatile("s_waitcnt vmcnt(" #VM ") lgkmcnt(0)" ::: "memory");  \
    __builtin_amdgcn_s_barrier();                                      \
  } while (0)

// ---------------------------------------------------------------------------
// Fused f32->bf16 conversion for x, Wqkv, Wproj in one launch.
// ---------------------------------------------------------------------------
__global__ __launch_bounds__(256) void cvt3(
    const float* __restrict__ x, const float* __restrict__ wa,
    const float* __restrict__ wp, ushort_t* __restrict__ xb,
    ushort_t* __restrict__ wab, ushort_t* __restrict__ wpb)
{
  const int n1 = (8192 * 768) / 4, n2 = (2304 * 768) / 4;
  int i = blockIdx.x * 256 + threadIdx.x;
  const float* in; ushort_t* out;
  if (i < n1)            { in = x;  out = xb; }
  else if (i < n1 + n2)  { in = wa; out = wab; i -= n1; }
  else                   { in = wp; out = wpb; i -= (n1 + n2); }
  float4 v = *(const float4*)(in + (size_t)i * 4);
  ushort4v o;
  o.x = f2bf(v.x); o.y = f2bf(v.y); o.z = f2bf(v.z); o.w = f2bf(v.w);
  *(ushort4v*)(out + (size_t)i * 4) = o;
}

// ---------------------------------------------------------------------------
// Shared GEMM machinery: 128x128 tile, BK=32, 4 waves 2x2, 3 SEPARATE LDS
// buffers, 2-deep prefetch with counted vmcnt(4). K = 768 (24 steps), fully
// static buffer rotation.
// ---------------------------------------------------------------------------
#define GSTAGE(LA, LB, OFF)                                            \
  do {                                                                 \
    GLOAD16(gA + (OFF), &LA[wid * 512]);                               \
    GLOAD16(gA + (OFF) + (size_t)64 * 768, &LA[wid * 512 + 64 * 32]);  \
    GLOAD16(gB + (OFF), &LB[wid * 512]);                               \
    GLOAD16(gB + (OFF) + (size_t)64 * 768, &LB[wid * 512 + 64 * 32]);  \
  } while (0)

#define GCOMP(LA, LB)                                                  \
  do {                                                                 \
    short8 af[4], bf[4];                                               \
    _Pragma("unroll")                                                  \
    for (int t_ = 0; t_ < 4; ++t_) {                                   \
      af[t_] = *(const short8*)&LA[(wm + t_ * 16 + l15) * 32 + sw];    \
      bf[t_] = *(const short8*)&LB[(wn + t_ * 16 + l15) * 32 + sw];    \
    }                                                                  \
    __builtin_amdgcn_s_setprio(1);                                     \
    _Pragma("unroll")                                                  \
    for (int tm = 0; tm < 4; ++tm)                                     \
      _Pragma("unroll")                                                \
      for (int tn = 0; tn < 4; ++tn)                                   \
        acc[tm][tn] = MFMA16(af[tm], bf[tn], acc[tm][tn]);             \
    __builtin_amdgcn_s_setprio(0);                                     \
  } while (0)

// three steps t, t+1, t+2 (cur buffers 0,1,2; stage targets 2,0,1)
#define GK3(T)                                                         \
  WAITBAR(4); GSTAGE(As2, Bs2, ((T) + 2) * 32); GCOMP(As0, Bs0);       \
  WAITBAR(4); GSTAGE(As0, Bs0, ((T) + 3) * 32); GCOMP(As1, Bs1);       \
  WAITBAR(4); GSTAGE(As1, Bs1, ((T) + 4) * 32); GCOMP(As2, Bs2);

#define GEMM_KLOOP                                                     \
  GSTAGE(As0, Bs0, 0); GSTAGE(As1, Bs1, 32);                           \
  GK3(0) GK3(3) GK3(6) GK3(9) GK3(12) GK3(15) GK3(18)                  \
  WAITBAR(4); GSTAGE(As2, Bs2, 23 * 32); GCOMP(As0, Bs0);              \
  WAITBAR(4); GCOMP(As1, Bs1);                                         \
  WAITBAR(0); GCOMP(As2, Bs2);

#define GEMM_DECLS                                                     \
  __shared__ ushort_t As0[128 * 32], As1[128 * 32], As2[128 * 32];     \
  __shared__ ushort_t Bs0[128 * 32], Bs1[128 * 32], Bs2[128 * 32];     \
  const int tid  = threadIdx.x;                                        \
  const int lane = tid & 63;                                           \
  const int l15  = lane & 15;                                          \
  const int quad = lane >> 4;                                          \
  const int wid  = tid >> 6;                                           \
  const int m0 = blockIdx.x * 128;                                     \
  const int n0 = blockIdx.y * 128;                                     \
  const int wm = (wid >> 1) * 64;                                      \
  const int wn = (wid & 1) * 64;                                       \
  const int srow = tid >> 2;                                           \
  const int scol = (((tid & 3) ^ ((srow ^ (srow >> 2)) & 3))) * 8;     \
  const int sw = (quad ^ ((l15 ^ (l15 >> 2)) & 3)) * 8;                \
  floatx4 acc[4][4] = {};

// ---------------------------------------------------------------------------
// QKV GEMM: qkv = x @ Wqkv^T + b. Q columns pre-scaled by (1/sqrt(96))*log2e.
// Writes q,k into QK (row stride 1536) and v TRANSPOSED into VT[b][h][d][T]
// with time index sigma-permuted within each 64-block (attention needs no
// cross-lane P exchange).
// ---------------------------------------------------------------------------
__global__ __launch_bounds__(256) void gemm_qkv(
    const ushort_t* __restrict__ A,   // 8192 x 768 bf16 (x)
    const ushort_t* __restrict__ W,   // 2304 x 768 bf16
    const float* __restrict__ bias,   // 2304 f32
    ushort_t* __restrict__ QK,        // 8192 x 1536 bf16
    ushort_t* __restrict__ VT)        // (64 bh) x 96 x 1024 bf16 (perm cols)
{
  GEMM_DECLS;

  const ushort_t* gA = A + (size_t)(m0 + srow) * 768 + scol;
  const ushort_t* gB = W + (size_t)(n0 + srow) * 768 + scol;

  GEMM_KLOOP;

  const float QSCALE = 0.10206207261596577f * 1.4426950408889634f;

#pragma unroll
  for (int tn = 0; tn < 4; ++tn) {
    const int gc = n0 + wn + tn * 16 + l15;
    const float bv = bias[gc];
    const bool isv = (gc >= 1536);          // whole 16-col tile same side
    const bool isq = (gc < 768);
    const int hh = (gc - 1536) / 96, dd = (gc - 1536) % 96;
#pragma unroll
    for (int tm = 0; tm < 4; ++tm) {
      const int gr = m0 + wm + tm * 16 + quad * 4;
#pragma unroll
      for (int r = 0; r < 4; ++r) {
        float val = acc[tm][tn][r] + bv;
        const int row = gr + r;
        if (!isv) {
          if (isq) val *= QSCALE;
          QK[(size_t)row * 1536 + gc] = f2bf(val);
        } else {
          const int bb = row >> 10, tt = row & 1023;
          // sigma: bit2 <- tt.bit4, bits4..3 <- tt.bits3..2
          const int tt2 = (tt & ~0x1C) | (((tt >> 4) & 1) << 2) |
                          (((tt >> 2) & 3) << 3);
          VT[(((size_t)(bb * 8 + hh)) * 96 + dd) * 1024 + tt2] = f2bf(val);
        }
      }
    }
  }
}

// ---------------------------------------------------------------------------
// Generic GEMM (proj): C[m][n] = sum_k A[m][k] W[n][k] + bias[n], f32 out.
// K = 768 fixed. Same counted pipeline.
// ---------------------------------------------------------------------------
__global__ __launch_bounds__(256) void gemm_proj(
    const ushort_t* __restrict__ A,   // M x 768 bf16
    const ushort_t* __restrict__ W,   // N x 768 bf16
    const float* __restrict__ bias,   // N f32
    float* __restrict__ C,            // M x N f32
    int M, int N)
{
  GEMM_DECLS;

  const ushort_t* gA = A + (size_t)(m0 + srow) * 768 + scol;
  const ushort_t* gB = W + (size_t)(n0 + srow) * 768 + scol;

  GEMM_KLOOP;

#pragma unroll
  for (int tn = 0; tn < 4; ++tn) {
    const int gc = n0 + wn + tn * 16 + l15;
    const float bv = bias[gc];
#pragma unroll
    for (int tm = 0; tm < 4; ++tm) {
      const int gr = m0 + wm + tm * 16 + quad * 4;
#pragma unroll
      for (int r = 0; r < 4; ++r)
        C[(size_t)(gr + r) * N + gc] = acc[tm][tn][r] + bv;
    }
  }
}

// ---------------------------------------------------------------------------
// Fused causal flash attention, swapped-QK^T form, counted-vmcnt pipeline,
// SEPARATE named K/V buffers with a x2-unrolled main loop (static buffers).
// Grid (16, 64): block = (b,h) + paired q-chunks cA=bx, cB=31-cA (32 rows ea).
// Waves 0,1 -> chunk A rows; waves 2,3 -> chunk B rows (16 q-rows per wave).
// ---------------------------------------------------------------------------
#define ATTN_COMPUTE(KS, VTC, K0)                                      \
  do {                                                                 \
    floatx4 s[4] = {};                                                 \
    __builtin_amdgcn_s_setprio(1);                                     \
    _Pragma("unroll")                                                  \
    for (int t = 0; t < 4; ++t) {                                      \
      _Pragma("unroll")                                                \
      for (int c = 0; c < 3; ++c) {                                    \
        short8 kf = *(const short8*)                                   \
            &KS[(t * 16 + l15) * 96 + c * 32 + quad * 8];              \
        s[t] = MFMA16(kf, qf[c], s[t]);                                \
      }                                                                \
    }                                                                  \
    __builtin_amdgcn_s_setprio(0);                                     \
    float p[4][4];                                                     \
    if ((K0) + 64 <= q0w) {                                            \
      _Pragma("unroll")                                                \
      for (int t = 0; t < 4; ++t)                                      \
        _Pragma("unroll")                                              \
        for (int j = 0; j < 4; ++j) p[t][j] = s[t][j];                 \
    } else {                                                           \
      const int kq = (K0) + quad * 4;                                  \
      _Pragma("unroll")                                                \
      for (int t = 0; t < 4; ++t)                                      \
        _Pragma("unroll")                                              \
        for (int j = 0; j < 4; ++j)                                    \
          p[t][j] = (kq + t * 16 + j <= rq) ? s[t][j] : NEG_BIG;       \
    }                                                                  \
    float m0v = fmaxf(fmaxf(p[0][0], p[0][1]), fmaxf(p[0][2], p[0][3]));\
    float m1v = fmaxf(fmaxf(p[1][0], p[1][1]), fmaxf(p[1][2], p[1][3]));\
    float m2v = fmaxf(fmaxf(p[2][0], p[2][1]), fmaxf(p[2][2], p[2][3]));\
    float m3v = fmaxf(fmaxf(p[3][0], p[3][1]), fmaxf(p[3][2], p[3][3]));\
    float mt = fmaxf(fmaxf(m0v, m1v), fmaxf(m2v, m3v));                \
    mt = fmaxf(mt, __shfl_xor(mt, 16));                                \
    mt = fmaxf(mt, __shfl_xor(mt, 32));                                \
    if (!__all(mt - m_i <= 8.0f)) {                                    \
      const float mn = fmaxf(m_i, mt);                                 \
      const float al = __builtin_amdgcn_exp2f(m_i - mn);               \
      m_i = mn;                                                        \
      l_i *= al;                                                       \
      _Pragma("unroll")                                                \
      for (int j = 0; j < 4; ++j) {                                    \
        const float alr = __shfl(al, quad * 4 + j);                    \
        _Pragma("unroll")                                              \
        for (int f = 0; f < 6; ++f) O[f][j] *= alr;                    \
      }                                                                \
    }                                                                  \
    float rs = 0.f;                                                    \
    _Pragma("unroll")                                                  \
    for (int t = 0; t < 4; ++t)                                        \
      _Pragma("unroll")                                                \
      for (int j = 0; j < 4; ++j) {                                    \
        p[t][j] = __builtin_amdgcn_exp2f(p[t][j] - m_i);               \
        rs += p[t][j];                                                 \
      }                                                                \
    rs += __shfl_xor(rs, 16);                                          \
    rs += __shfl_xor(rs, 32);                                          \
    l_i += rs;                                                         \
    union { short8 s8; unsigned int u[4]; } pf0, pf1;                  \
    pf0.u[0] = packbf2(p[0][0], p[0][1]);                              \
    pf0.u[1] = packbf2(p[0][2], p[0][3]);                              \
    pf0.u[2] = packbf2(p[1][0], p[1][1]);                              \
    pf0.u[3] = packbf2(p[1][2], p[1][3]);                              \
    pf1.u[0] = packbf2(p[2][0], p[2][1]);                              \
    pf1.u[1] = packbf2(p[2][2], p[2][3]);                              \
    pf1.u[2] = packbf2(p[3][0], p[3][1]);                              \
    pf1.u[3] = packbf2(p[3][2], p[3][3]);                              \
    __builtin_amdgcn_s_setprio(1);                                     \
    _Pragma("unroll")                                                  \
    for (int f = 0; f < 6; ++f) {                                      \
      short8 vf0 = *(const short8*)&VTC[(f * 16 + l15) * 72 + quad * 8];\
      O[f] = MFMA16(pf0.s8, vf0, O[f]);                                \
      short8 vf1 = *(const short8*)                                    \
          &VTC[(f * 16 + l15) * 72 + 32 + quad * 8];                   \
      O[f] = MFMA16(pf1.s8, vf1, O[f]);                                \
    }                                                                  \
    __builtin_amdgcn_s_setprio(0);                                     \
  } while (0)

// one pipelined iteration (never the last): wait, stage K(t+1) into KSN,
// compute(t) from KS/VTC, write V(t+1) into VTN, load V(t+2) regs.
#define AITER(KS, VTC, KSN, VTN, K0)                                   \
  do {                                                                 \
    const int k0_ = (K0);                                              \
    const int nk_ = k0_ + 64;                                          \
    WAITBAR_LGKM(3);                                                   \
    _Pragma("unroll")                                                  \
    for (int i = 0; i < 3; ++i) {                                      \
      const int e = ke0 + i * 512;                                     \
      const int kr = e / 96, kc = e % 96;                              \
      GLOAD16(QK + (rowbase + nk_ + kr) * 1536 + 768 + qoff + kc,      \
              &KSN[wid * 1536 + i * 512]);                             \
    }                                                                  \
    if (k0_ < q0w + 16) { ATTN_COMPUTE(KS, VTC, k0_); }                \
    _Pragma("unroll")                                                  \
    for (int g = 0; g < 3; ++g)                                        \
      *(short8*)&VTN[(g * 32 + vd) * 72 + vkc] = vreg[g];              \
    if (nk_ + 64 < kend) {                                             \
      _Pragma("unroll")                                                \
      for (int g = 0; g < 3; ++g)                                      \
        vreg[g] = *(const short8*)                                     \
            (vtb + (size_t)(g * 32 + vd) * 1024 + nk_ + 64 + vkc);     \
    }                                                                  \
  } while (0)

#define AITER_LAST(KS, VTC, K0)                                        \
  do {                                                                 \
    WAITBAR_LGKM(0);                                                   \
    if ((K0) < q0w + 16) { ATTN_COMPUTE(KS, VTC, (K0)); }              \
  } while (0)

__global__ __launch_bounds__(256) void attn_fused(
    const ushort_t* __restrict__ QK,   // (B*T) x 1536 bf16  [q*scale | k]
    const ushort_t* __restrict__ VT,   // (64 bh) x 96 x 1024 bf16 (perm cols)
    ushort_t* __restrict__ y)          // (B*T) x 768 bf16
{
  __shared__ ushort_t Ks0[64 * 96], Ks1[64 * 96];
  __shared__ ushort_t Vt0[96 * 72], Vt1[96 * 72];

  const int tid  = threadIdx.x;
  const int lane = tid & 63;
  const int l15  = lane & 15;
  const int quad = lane >> 4;
  const int wid  = tid >> 6;
  const int bh = blockIdx.y;
  const int b = bh >> 3;
  const int h = bh & 7;
  const int qoff = h * 96;

  const int cA = blockIdx.x;           // 0..15
  const int cB = 31 - cA;              // 16..31
  const int myChunk = (wid < 2) ? cA : cB;
  const int q0w = myChunk * 32 + (wid & 1) * 16;   // wave's first q row
  const int kend = cB * 32 + 32;                   // loop bound (chunk B)
  const int rq = q0w + l15;                        // this lane's q row

  const size_t rowbase = (size_t)b * 1024;
  const ushort_t* vtb = VT + (size_t)bh * 96 * 1024;

  // per-thread staging coords
  const int ke0 = wid * 1536 + lane * 8;           // K-stage element base
  const int vd  = (tid >> 3);                      // V-stage row within group
  const int vkc = (tid & 7) * 8;                   // V-stage col

  // Q fragments (used as B operand), K=96 in 3 chunks of 32
  short8 qf[3];
#pragma unroll
  for (int c = 0; c < 3; ++c)
    qf[c] = *(const short8*)(QK + (rowbase + q0w + l15) * 1536 + qoff +
                             c * 32 + quad * 8);

  float m_i = NEG_BIG;   // running max for row l15 (exp2 domain)
  float l_i = 0.f;       // running denom for row l15
  floatx4 O[6] = {};

  short8 vreg[3];

  // prologue: V(0) regs FIRST, K(0) gloads, write V(0), issue V(1) regs.
#pragma unroll
  for (int g = 0; g < 3; ++g)
    vreg[g] = *(const short8*)(vtb + (size_t)(g * 32 + vd) * 1024 + vkc);
#pragma unroll
  for (int i = 0; i < 3; ++i) {
    const int e = ke0 + i * 512;
    const int kr = e / 96, kc = e % 96;
    GLOAD16(QK + (rowbase + kr) * 1536 + 768 + qoff + kc,
            &Ks0[wid * 1536 + i * 512]);
  }
#pragma unroll
  for (int g = 0; g < 3; ++g)
    *(short8*)&Vt0[(g * 32 + vd) * 72 + vkc] = vreg[g];
#pragma unroll
  for (int g = 0; g < 3; ++g)
    vreg[g] = *(const short8*)(vtb + (size_t)(g * 32 + vd) * 1024 + 64 + vkc);

  // main loop: pairs of tiles with static buffers; 1-or-2 iteration tail.
  int k0 = 0;
  while (k0 + 128 < kend) {
    AITER(Ks0, Vt0, Ks1, Vt1, k0);
    AITER(Ks1, Vt1, Ks0, Vt0, k0 + 64);
    k0 += 128;
  }
  if (k0 + 64 < kend) {
    AITER(Ks0, Vt0, Ks1, Vt1, k0);
    AITER_LAST(Ks1, Vt1, k0 + 64);
  } else {
    AITER_LAST(Ks0, Vt0, k0);
  }

  // epilogue: O rows are quad*4+j; softmax denom lives in lane (row)
  float inv[4];
#pragma unroll
  for (int j = 0; j < 4; ++j) {
    const float lj = __shfl(l_i, quad * 4 + j);
    inv[j] = 1.0f / fmaxf(lj, 1e-20f);
  }
#pragma unroll
  for (int j = 0; j < 4; ++j) {
    const size_t row = rowbase + q0w + quad * 4 + j;
#pragma unroll
    for (int f = 0; f < 6; ++f)
      y[row * 768 + qoff + f * 16 + l15] = f2bf(O[f][j] * inv[j]);
  }
}

// ---------------------------------------------------------------------------
extern "C" void kernel_launch(void* const* d_in, const int* in_sizes, int n_in,
                              void* d_out, int out_size, void* d_ws, size_t ws_size,
                              hipStream_t stream)
{
  const float* x_f  = (const float*)d_in[0];
  const float* wa_f = (const float*)d_in[1];
  const float* ba_f = (const float*)d_in[2];
  const float* wp_f = (const float*)d_in[3];
  const float* bp_f = (const float*)d_in[4];
  float* out = (float*)d_out;

  ushort_t* xb  = (ushort_t*)d_ws;                    // 8192 x  768
  ushort_t* wab = xb  + (size_t)8192 * 768;           // 2304 x  768
  ushort_t* wpb = wab + (size_t)2304 * 768;           //  768 x  768
  ushort_t* QK  = wpb + (size_t)768 * 768;            // 8192 x 1536
  ushort_t* VT  = QK  + (size_t)8192 * 1536;          // 64 x 96 x 1024
  ushort_t* yw  = VT  + (size_t)8192 * 768;           // 8192 x  768

  // (8192*768 + 2304*768 + 768*768)/4 = 2162688 = 8448 * 256
  cvt3<<<8448, 256, 0, stream>>>(x_f, wa_f, wp_f, xb, wab, wpb);

  gemm_qkv<<<dim3(64, 18), 256, 0, stream>>>(xb, wab, ba_f, QK, VT);
  attn_fused<<<dim3(16, 64), 256, 0, stream>>>(QK, VT, yw);
  gemm_proj<<<dim3(64, 6), 256, 0, stream>>>(yw, wpb, bp_f, out,
                                             8192, 768);
}